// Round 3
// baseline (12723.617 us; speedup 1.0000x reference)
//
#include <hip/hip_runtime.h>
#include <math.h>

#define NHH 48
#define NNN 384
#define NP  18432   // NHH*NNN
#define NEC 1024
#define CHUNK 2304  // NP/8, = 6 complete h-groups of 384 rows
#define NCH 8
#define HPC 6       // h-groups per chunk (CHUNK / NNN)

// ---------------------------------------------------------------------------
// Generic f32 GEMM: C[M,N] = epilogue(A[M,K] @ B + bias)
// lda == K, ldc == N always in this problem.
// B layout: ldbBlock==0 -> row-major [K,N]. Else column-block-of-64 ("head"
// weights (16,K,64)): block bx covers cols [bx*64,(bx+1)*64), base = B + bx*ldbBlock.
// MODE 0: C = maybe_relu(acc + bias)
// MODE 1: adj partial: part[row*16+bx] = sum_j relu(acc+bias[j])*wadj[j]
// MODE 2: row-remapped store to out[orow*2048 + colofs + j], relu, skip diag pairs
//         (global row = rowbase + local row)
// MODE 3: C = relu(ug[j] * (acc + bias[j]))
// ---------------------------------------------------------------------------
template<int MODE>
__global__ __launch_bounds__(256) void gemm_k(
    const float* __restrict__ A, const float* __restrict__ B, long long ldbBlock,
    float* __restrict__ C, int M, int N, int K,
    const float* __restrict__ bias, int do_relu,
    const float* __restrict__ ug, const float* __restrict__ wadj,
    float* __restrict__ part, int colofs, int rowbase)
{
  const int tid = threadIdx.x;
  const int tx = tid & 15, ty = tid >> 4;
  const int m0 = blockIdx.y * 64, n0 = blockIdx.x * 64;
  __shared__ float As[16][64];
  __shared__ float Bs[16][64];
  const int ldb = ldbBlock ? 64 : N;
  const float* Bp = ldbBlock ? (B + (long long)blockIdx.x * ldbBlock) : (B + n0);
  float acc[4][4] = {};
  const int arow = tid >> 2;          // 0..63
  const int acol = (tid & 3) * 4;     // 0,4,8,12
  const int brow = tid >> 4;          // 0..15
  const int bcol = (tid & 15) * 4;    // 0..60

  for (int k0 = 0; k0 < K; k0 += 16) {
    {
      int gm = m0 + arow;
#pragma unroll
      for (int u = 0; u < 4; ++u) {
        int gk = k0 + acol + u;
        float v = 0.f;
        if (gm < M && gk < K) v = A[(long long)gm * K + gk];
        As[acol + u][arow] = v;
      }
    }
    {
      int gk = k0 + brow;
      const float* src = Bp + (long long)gk * ldb + bcol;
#pragma unroll
      for (int u = 0; u < 4; ++u) {
        float v = 0.f;
        if (gk < K) v = src[u];
        Bs[brow][bcol + u] = v;
      }
    }
    __syncthreads();
#pragma unroll
    for (int kk = 0; kk < 16; ++kk) {
      float a[4], b[4];
#pragma unroll
      for (int i = 0; i < 4; ++i) a[i] = As[kk][ty * 4 + i];
#pragma unroll
      for (int j = 0; j < 4; ++j) b[j] = Bs[kk][tx * 4 + j];
#pragma unroll
      for (int i = 0; i < 4; ++i)
#pragma unroll
        for (int j = 0; j < 4; ++j)
          acc[i][j] = fmaf(a[i], b[j], acc[i][j]);
    }
    __syncthreads();
  }

  if constexpr (MODE == 0) {
#pragma unroll
    for (int i = 0; i < 4; ++i) {
      int gm = m0 + ty * 4 + i;
      if (gm >= M) continue;
#pragma unroll
      for (int j = 0; j < 4; ++j) {
        int jg = n0 + tx * 4 + j;
        float v = acc[i][j] + (bias ? bias[jg] : 0.f);
        if (do_relu) v = fmaxf(v, 0.f);
        C[(long long)gm * N + jg] = v;
      }
    }
  } else if constexpr (MODE == 3) {
#pragma unroll
    for (int i = 0; i < 4; ++i) {
      int gm = m0 + ty * 4 + i;
      if (gm >= M) continue;
#pragma unroll
      for (int j = 0; j < 4; ++j) {
        int jg = n0 + tx * 4 + j;
        float v = fmaxf(ug[jg] * (acc[i][j] + bias[jg]), 0.f);
        C[(long long)gm * N + jg] = v;
      }
    }
  } else if constexpr (MODE == 2) {
#pragma unroll
    for (int i = 0; i < 4; ++i) {
      int gm = m0 + ty * 4 + i;
      if (gm >= M) continue;
      int gmg = rowbase + gm;
      int h = gmg / NNN, n = gmg - h * NNN;
      if (n == h) continue;                 // diagonal pair removed
      long long orow = gmg - h - (n > h ? 1 : 0);
#pragma unroll
      for (int j = 0; j < 4; ++j) {
        int jg = n0 + tx * 4 + j;
        float v = fmaxf(acc[i][j] + bias[jg], 0.f);
        C[orow * 2048 + colofs + jg] = v;
      }
    }
  } else if constexpr (MODE == 1) {
    __shared__ float red[64][17];
#pragma unroll
    for (int i = 0; i < 4; ++i) {
      float s = 0.f;
#pragma unroll
      for (int j = 0; j < 4; ++j) {
        int jg = n0 + tx * 4 + j;
        float v = fmaxf(acc[i][j] + bias[jg], 0.f);
        s = fmaf(v, wadj[jg], s);
      }
      red[ty * 4 + i][tx] = s;
    }
    __syncthreads();
    if (tid < 64) {
      float s = 0.f;
#pragma unroll
      for (int t = 0; t < 16; ++t) s += red[tid][t];
      int gm = m0 + tid;
      if (gm < M) part[(long long)gm * 16 + blockIdx.x] = s;
    }
  }
}

// V[p_local,:] = relu((uh[h,:] + un[n,:]) * V[p_local,:]), global p = rowbase+p_local
__global__ __launch_bounds__(256) void tmul_k(float* __restrict__ V,
    const float* __restrict__ uh, const float* __restrict__ un, int rowbase)
{
  int pl = blockIdx.x;
  int pg = rowbase + pl;
  int h = pg / NNN, n = pg - h * NNN;
  const float* uhr = uh + (long long)h * NEC;
  const float* unr = un + (long long)n * NEC;
  float* Vr = V + (long long)pl * NEC;
  for (int j = threadIdx.x; j < NEC; j += 256) {
    float u = uhr[j] + unr[j];
    Vr[j] = fmaxf(u * Vr[j], 0.f);
  }
}

// tw[h,j] = sum_n soft[h,n] * relu(uO[n,j] * V[(h_l*384+n),j]),  h = h0 + h_l
__global__ __launch_bounds__(256) void tw_k(const float* __restrict__ V,
    const float* __restrict__ uO, const float* __restrict__ soft,
    float* __restrict__ tw, int h0)
{
  int hl = blockIdx.x;
  int h = h0 + hl;
  int j = blockIdx.y * 256 + threadIdx.x;
  const float* srow = soft + h * NNN;
  float s = 0.f;
  for (int n = 0; n < NNN; ++n) {
    float t = fmaxf(uO[(long long)n * NEC + j] * V[((long long)hl * NNN + n) * NEC + j], 0.f);
    s = fmaf(srow[n], t, s);
  }
  tw[(long long)h * NEC + j] = s;
}

// two[n,j] (+)= sum_{h_l<HPC} softT[n, h0+h_l] * relu(uS[h0+h_l,j] * V[(h_l*384+n),j])
__global__ __launch_bounds__(256) void two_k(const float* __restrict__ V,
    const float* __restrict__ uS, const float* __restrict__ softT,
    float* __restrict__ two, int h0, int accum)
{
  int n = blockIdx.x;
  int j = blockIdx.y * 256 + threadIdx.x;
  const float* srow = softT + n * NHH;
  float s = 0.f;
#pragma unroll
  for (int hl = 0; hl < HPC; ++hl) {       // FIXED: was a mis-parenthesized ternary running 8 iters
    int h = h0 + hl;
    float t = fmaxf(uS[(long long)h * NEC + j] * V[((long long)hl * NNN + n) * NEC + j], 0.f);
    s = fmaf(srow[h], t, s);
  }
  long long idx = (long long)n * NEC + j;
  two[idx] = accum ? (two[idx] + s) : s;
}

__global__ void adjfin_k(const float* __restrict__ part, const float* __restrict__ badj,
                         float* __restrict__ adj)
{
  int p = blockIdx.x * blockDim.x + threadIdx.x;
  if (p < NP) {
    float s = badj[0];
#pragma unroll
    for (int c = 0; c < 16; ++c) s += part[(long long)p * 16 + c];
    adj[p] = s;
  }
}

__global__ __launch_bounds__(64) void softmax_row_k(const float* __restrict__ adj,
                                                    float* __restrict__ soft)
{
  __shared__ float buf[NNN];
  int h = blockIdx.x, t = threadIdx.x;
  float mx = -1e30f;
  for (int n = t; n < NNN; n += 64) { float v = adj[h * NNN + n]; buf[n] = v; mx = fmaxf(mx, v); }
#pragma unroll
  for (int off = 32; off >= 1; off >>= 1) mx = fmaxf(mx, __shfl_xor(mx, off));
  float s = 0.f;
  for (int n = t; n < NNN; n += 64) { float e = expf(buf[n] - mx); buf[n] = e; s += e; }
#pragma unroll
  for (int off = 32; off >= 1; off >>= 1) s += __shfl_xor(s, off);
  float inv = 1.f / s;
  for (int n = t; n < NNN; n += 64) soft[h * NNN + n] = buf[n] * inv;
}

__global__ __launch_bounds__(64) void softmaxT_k(const float* __restrict__ adj,
                                                 float* __restrict__ softT)
{
  int n = blockIdx.x, t = threadIdx.x;
  float v = (t < NHH) ? adj[t * NNN + n] : -1e30f;
  float mx = v;
#pragma unroll
  for (int off = 32; off >= 1; off >>= 1) mx = fmaxf(mx, __shfl_xor(mx, off));
  float e = (t < NHH) ? expf(v - mx) : 0.f;
  float s = e;
#pragma unroll
  for (int off = 32; off >= 1; off >>= 1) s += __shfl_xor(s, off);
  if (t < NHH) softT[n * NHH + t] = e / s;
}

// out[r,:] = LN(x[r,:] + m[r,:]) * g + b
__global__ __launch_bounds__(256) void ln_k(const float* __restrict__ x, const float* __restrict__ m,
    const float* __restrict__ g, const float* __restrict__ b, float* __restrict__ out)
{
  int r = blockIdx.x, t = threadIdx.x;
  __shared__ float rs[4], rs2[4];
  const float* xr = x + (long long)r * NEC;
  const float* mr = m + (long long)r * NEC;
  float s = 0.f, s2 = 0.f;
  for (int j = t; j < NEC; j += 256) { float v = xr[j] + mr[j]; s += v; s2 = fmaf(v, v, s2); }
#pragma unroll
  for (int off = 32; off >= 1; off >>= 1) { s += __shfl_xor(s, off); s2 += __shfl_xor(s2, off); }
  if ((t & 63) == 0) { rs[t >> 6] = s; rs2[t >> 6] = s2; }
  __syncthreads();
  s = rs[0] + rs[1] + rs[2] + rs[3];
  s2 = rs2[0] + rs2[1] + rs2[2] + rs2[3];
  float mean = s * (1.f / NEC);
  float var = s2 * (1.f / NEC) - mean * mean;
  float rstd = rsqrtf(var + 1e-5f);
  float* o = out + (long long)r * NEC;
  for (int j = t; j < NEC; j += 256) {
    float v = xr[j] + mr[j];
    o[j] = (v - mean) * rstd * g[j] + b[j];
  }
}

__global__ __launch_bounds__(64) void gfeat_k(const float* __restrict__ feat3,
                                              float* __restrict__ gfeat)
{
  int ch = blockIdx.x, t = threadIdx.x;
  float s = 0.f;
  for (int i = t; i < 625; i += 64) s += feat3[ch * 625 + i];
#pragma unroll
  for (int off = 32; off >= 1; off >>= 1) s += __shfl_xor(s, off);
  if (t == 0) gfeat[ch] = s * (1.f / 625.f);
}

__global__ __launch_bounds__(256) void b3sum_k(const float* __restrict__ b3,
                                               float* __restrict__ out)
{
  int r = blockIdx.x * 256 + threadIdx.x;
  if (r < NEC) {
    float s = 0.f;
#pragma unroll
    for (int c = 0; c < 16; ++c) s += b3[c * NEC + r];
    out[r] = s;
  }
}

extern "C" void kernel_launch(void* const* d_in, const int* in_sizes, int n_in,
                              void* d_out, int out_size, void* d_ws, size_t ws_size,
                              hipStream_t stream)
{
  const float* box   = (const float*)d_in[0];
  const float* feat3 = (const float*)d_in[1];
  const float* sp36  = (const float*)d_in[2];
  const float* Wbh1  = (const float*)d_in[3];
  const float* bbh1  = (const float*)d_in[4];
  const float* Wbh2  = (const float*)d_in[5];
  const float* bbh2  = (const float*)d_in[6];
  const float* Wsp1  = (const float*)d_in[7];
  const float* bsp1  = (const float*)d_in[8];
  const float* Wsp2  = (const float*)d_in[9];
  const float* bsp2  = (const float*)d_in[10];
  const float* Wsp3  = (const float*)d_in[11];
  const float* bsp3  = (const float*)d_in[12];
  const float* Wadj  = (const float*)d_in[13];
  const float* badj  = (const float*)d_in[14];
  const float* A1W = (const float*)d_in[15]; const float* A1b = (const float*)d_in[16];
  const float* A2W = (const float*)d_in[17]; const float* A2b = (const float*)d_in[18];
  const float* A3W = (const float*)d_in[19]; const float* A3b = (const float*)d_in[20];
  const float* O1W = (const float*)d_in[21]; const float* O1b = (const float*)d_in[22];
  const float* O2W = (const float*)d_in[23]; const float* O2b = (const float*)d_in[24];
  const float* O3W = (const float*)d_in[25]; const float* O3b = (const float*)d_in[26];
  const float* S1W = (const float*)d_in[27]; const float* S1b = (const float*)d_in[28];
  const float* S2W = (const float*)d_in[29]; const float* S2b = (const float*)d_in[30];
  const float* S3W = (const float*)d_in[31]; const float* S3b = (const float*)d_in[32];
  const float* G1W = (const float*)d_in[33]; const float* G1b = (const float*)d_in[34];
  const float* G2W = (const float*)d_in[35]; const float* G2b = (const float*)d_in[36];
  const float* G3W = (const float*)d_in[37]; const float* G3b = (const float*)d_in[38];
  const float* gln_h = (const float*)d_in[39]; const float* bln_h = (const float*)d_in[40];
  const float* gln_o = (const float*)d_in[41]; const float* bln_o = (const float*)d_in[42];
  (void)in_sizes; (void)n_in; (void)out_size; (void)ws_size;

  float* w = (float*)d_ws;
  size_t off = 0;
  auto alloc = [&](size_t nelem) { float* p = w + off; off += nelem; return p; };
  // ---- ~100 MB total ----
  float* SP    = alloc((size_t)NP * NEC);      // 75.5 MB, lives whole call
  float* Vc    = alloc((size_t)CHUNK * NEC);   // 9.4 MB per-chunk scratch
  float* s1c   = Vc;                            // aliases inside Vc (sp MLP staging)
  float* s2c   = Vc + (size_t)CHUNK * 128;
  float* node1 = alloc(384 * NEC);
  float* node  = alloc(384 * NEC);
  float* hnode1= alloc(48 * NEC);
  float* node2 = alloc(384 * NEC);
  float* uhA   = alloc(48 * NEC);
  float* unA   = alloc(384 * NEC);
  float* uO    = alloc(384 * NEC);
  float* uS    = alloc(48 * NEC);
  float* uh2   = alloc(48 * NEC);
  float* un2   = alloc(384 * NEC);
  float* uG    = alloc(NEC);
  float* gfeat = alloc(256);
  float* b3A = alloc(NEC); float* b3O = alloc(NEC); float* b3S = alloc(NEC); float* b3G = alloc(NEC);
  float* part  = alloc((size_t)NP * 16);
  float* adj   = alloc(NP);
  float* soft  = alloc(NP);
  float* softT = alloc(NP);
  float* twb   = alloc(48 * NEC);
  float* twob  = alloc(384 * NEC);
  float* m_h   = alloc(48 * NEC);
  float* m_o   = alloc(384 * NEC);

  auto gemm0 = [&](const float* A, const float* B, long long ldbB, float* C,
                   int M, int N, int K, const float* bias, int relu) {
    dim3 grid(N / 64, (M + 63) / 64);
    hipLaunchKernelGGL((gemm_k<0>), grid, dim3(256), 0, stream,
                       A, B, ldbB, C, M, N, K, bias, relu,
                       (const float*)nullptr, (const float*)nullptr, (float*)nullptr, 0, 0);
  };

  gfeat_k<<<256, 64, 0, stream>>>(feat3, gfeat);
  b3sum_k<<<4, 256, 0, stream>>>(A3b, b3A);
  b3sum_k<<<4, 256, 0, stream>>>(O3b, b3O);
  b3sum_k<<<4, 256, 0, stream>>>(S3b, b3S);
  b3sum_k<<<4, 256, 0, stream>>>(G3b, b3G);

  // node MLP
  gemm0(box, Wbh1, 0, node1, 384, NEC, 12544, bbh1, 1);
  gemm0(node1, Wbh2, 0, node, 384, NEC, NEC, bbh2, 1);

  // spatial MLP, chunked through Vc staging
  for (int c = 0; c < NCH; ++c) {
    int rb = c * CHUNK;
    gemm0(sp36 + (long long)rb * 36, Wsp1, 0, s1c, CHUNK, 128, 36, bsp1, 1);
    gemm0(s1c, Wsp2, 0, s2c, CHUNK, 256, 128, bsp2, 1);
    gemm0(s2c, Wsp3, 0, SP + (long long)rb * NEC, CHUNK, NEC, 256, bsp3, 1);
  }

  // ---- adjacency head (A), chunked ----
  gemm0(node, A1W, 2048LL * 64, uhA, 48, NEC, NEC, A1b, 0);
  gemm0(node, A1W + 1024 * 64, 2048LL * 64, unA, 384, NEC, NEC, nullptr, 0);
  for (int c = 0; c < NCH; ++c) {
    int rb = c * CHUNK;
    gemm0(SP + (long long)rb * NEC, A2W, 1024LL * 64, Vc, CHUNK, NEC, NEC, A2b, 0);
    tmul_k<<<CHUNK, 256, 0, stream>>>(Vc, uhA, unA, rb);
    dim3 grid(16, CHUNK / 64);
    hipLaunchKernelGGL((gemm_k<1>), grid, dim3(256), 0, stream,
                       Vc, A3W, 0LL, (float*)nullptr, CHUNK, NEC, NEC, b3A, 1,
                       (const float*)nullptr, Wadj, part + (long long)rb * 16, 0, 0);
  }
  adjfin_k<<<(NP + 255) / 256, 256, 0, stream>>>(part, badj, adj);
  softmax_row_k<<<NHH, 64, 0, stream>>>(adj, soft);
  softmaxT_k<<<NNN, 64, 0, stream>>>(adj, softT);

  // ---- m_h (O head), chunked ----
  gemm0(node, O1W, 1024LL * 64, uO, 384, NEC, NEC, O1b, 0);
  for (int c = 0; c < NCH; ++c) {
    int rb = c * CHUNK;
    gemm0(SP + (long long)rb * NEC, O2W, 1024LL * 64, Vc, CHUNK, NEC, NEC, O2b, 0);
    tw_k<<<dim3(HPC, 4), 256, 0, stream>>>(Vc, uO, soft, twb, c * HPC);
  }
  gemm0(twb, O3W, 0, m_h, 48, NEC, NEC, b3O, 1);
  ln_k<<<NHH, 256, 0, stream>>>(node, m_h, gln_h, bln_h, hnode1);

  // ---- m_o (S head), chunked with accumulation ----
  gemm0(hnode1, S1W, 1024LL * 64, uS, 48, NEC, NEC, S1b, 0);
  for (int c = 0; c < NCH; ++c) {
    int rb = c * CHUNK;
    gemm0(SP + (long long)rb * NEC, S2W, 1024LL * 64, Vc, CHUNK, NEC, NEC, S2b, 0);
    two_k<<<dim3(NNN, 4), 256, 0, stream>>>(Vc, uS, softT, twob, c * HPC, c > 0);
  }
  gemm0(twob, S3W, 0, m_o, 384, NEC, NEC, b3S, 1);
  ln_k<<<NNN, 256, 0, stream>>>(node, m_o, gln_o, bln_o, node2);

  // ---- f_pair (A head on updated nodes), chunked ----
  gemm0(hnode1, A1W, 2048LL * 64, uh2, 48, NEC, NEC, A1b, 0);
  gemm0(node2, A1W + 1024 * 64, 2048LL * 64, un2, 384, NEC, NEC, nullptr, 0);
  for (int c = 0; c < NCH; ++c) {
    int rb = c * CHUNK;
    gemm0(SP + (long long)rb * NEC, A2W, 1024LL * 64, Vc, CHUNK, NEC, NEC, A2b, 0);
    tmul_k<<<CHUNK, 256, 0, stream>>>(Vc, uh2, un2, rb);
    dim3 grid(16, CHUNK / 64);
    hipLaunchKernelGGL((gemm_k<2>), grid, dim3(256), 0, stream,
                       Vc, A3W, 0LL, (float*)d_out, CHUNK, NEC, NEC, b3A, 1,
                       (const float*)nullptr, (const float*)nullptr, (float*)nullptr, 0, rb);
  }

  // ---- f_glob (G head), chunked ----
  gemm0(gfeat, G1W, 256LL * 64, uG, 1, NEC, 256, G1b, 0);
  for (int c = 0; c < NCH; ++c) {
    int rb = c * CHUNK;
    dim3 grid(16, CHUNK / 64);
    hipLaunchKernelGGL((gemm_k<3>), grid, dim3(256), 0, stream,
                       SP + (long long)rb * NEC, G2W, 1024LL * 64, Vc, CHUNK, NEC, NEC, G2b, 0,
                       uG, (const float*)nullptr, (float*)nullptr, 0, 0);
    hipLaunchKernelGGL((gemm_k<2>), grid, dim3(256), 0, stream,
                       Vc, G3W, 0LL, (float*)d_out, CHUNK, NEC, NEC, b3G, 1,
                       (const float*)nullptr, (const float*)nullptr, (float*)nullptr, 1024, rb);
  }
}

// Round 4
// 8827.272 us; speedup vs baseline: 1.4414x; 1.4414x over previous
//
#include <hip/hip_runtime.h>
#include <math.h>

#define NHH 48
#define NNN 384
#define NP  18432   // NHH*NNN
#define NEC 1024
#define CHUNK 2304  // NP/8, = 6 complete h-groups of 384 rows
#define NCH 8
#define HPC 6       // h-groups per chunk

#define BM 128
#define BN 128
#define BK 32
#define KPAD 40     // padded bf16 elems per LDS row (80B: 8-aligned, bank-spread)

typedef __attribute__((ext_vector_type(8))) short short8v;   // 8 bf16 (4 VGPR)
typedef __attribute__((ext_vector_type(4))) float f32x4;     // MFMA acc

__device__ __forceinline__ unsigned short f2bf(float x) {
  unsigned int u = __float_as_uint(x);
  u += 0x7fffu + ((u >> 16) & 1u);   // round-to-nearest-even
  return (unsigned short)(u >> 16);
}

// ---------------------------------------------------------------------------
// bf16-MFMA GEMM: C[M,N] = epilogue(A[M,K] @ B + bias), A/B are f32 in memory,
// converted to bf16 during LDS staging; f32 accumulate.
// B layout: ldbBlock==0 -> row-major [K,N]; else column-block-64 head weights:
// global col gc lives in block gc>>6 at (B + (gc>>6)*ldbBlock)[k*64 + (gc&63)].
// MODE 0: C = maybe_relu(acc + bias)
// MODE 1: part[gm*8 + bx] = sum_j relu(acc+bias[j])*wadj[j]   (adj partials)
// MODE 2: out[orow*2048 + colofs + j] = relu(acc+bias[j]), skip diag pairs
// MODE 3: C = relu(ug[j] * (acc + bias[j]))
// Tile: 128x128, BK=32, 256 thr = 4 waves, each wave 64x64 via 4x4 mfma 16x16x32.
// ---------------------------------------------------------------------------
template<int MODE>
__global__ __launch_bounds__(256) void gemm_mfma(
    const float* __restrict__ A, const float* __restrict__ B, long long ldbBlock,
    float* __restrict__ C, int M, int N, int K,
    const float* __restrict__ bias, int do_relu,
    const float* __restrict__ ug, const float* __restrict__ wadj,
    float* __restrict__ part, int colofs, int rowbase)
{
  __shared__ unsigned short As[BM * KPAD];   // As[m][k]
  __shared__ unsigned short Bs[BN * KPAD];   // Bs[n][k]  (B staged transposed)
  __shared__ float red2[BM][2];              // MODE1 cross-wave reduce

  const int tid  = threadIdx.x;
  const int lane = tid & 63;
  const int wave = tid >> 6;
  const int wr = wave >> 1, wc = wave & 1;   // wave's 64x64 quadrant
  const int lm = lane & 15;                  // col (B/D) or row (A) within 16
  const int kg = lane >> 4;                  // k-group (0..3)
  const int m0 = blockIdx.y * BM, n0 = blockIdx.x * BN;

  f32x4 acc[4][4];
#pragma unroll
  for (int i = 0; i < 4; ++i)
#pragma unroll
    for (int j = 0; j < 4; ++j)
      acc[i][j] = (f32x4){0.f, 0.f, 0.f, 0.f};

  // B source for this thread's staged column
  const int bn = tid & 127;                  // col within tile
  const int kb = (tid >> 7) * 16;            // 0 or 16
  const float* bsrc;
  long long bstride;
  {
    int gcol = n0 + bn;                      // N is always a multiple of 128
    if (ldbBlock) {
      bsrc = B + (long long)(gcol >> 6) * ldbBlock + (gcol & 63);
      bstride = 64;
    } else {
      bsrc = B + gcol;
      bstride = N;
    }
  }

  for (int k0 = 0; k0 < K; k0 += BK) {
    // ---- stage A tile (BM x BK): vector f32 loads, bf16 convert ----
#pragma unroll
    for (int j = 0; j < 4; ++j) {
      int m = (tid >> 3) + j * 32;
      int k = (tid & 7) * 4;
      int gm = m0 + m, gk = k0 + k;
      float x0 = 0.f, x1 = 0.f, x2 = 0.f, x3 = 0.f;
      if (gm < M) {
        const float* src = A + (long long)gm * K + gk;
        if (gk + 3 < K) { float4 v = *(const float4*)src; x0 = v.x; x1 = v.y; x2 = v.z; x3 = v.w; }
        else {
          if (gk     < K) x0 = src[0];
          if (gk + 1 < K) x1 = src[1];
          if (gk + 2 < K) x2 = src[2];
          if (gk + 3 < K) x3 = src[3];
        }
      }
      uint2 w2;
      w2.x = (unsigned)f2bf(x0) | ((unsigned)f2bf(x1) << 16);
      w2.y = (unsigned)f2bf(x2) | ((unsigned)f2bf(x3) << 16);
      *(uint2*)&As[m * KPAD + k] = w2;
    }
    // ---- stage B tile (BK x BN) transposed into Bs[n][k] ----
    {
      unsigned pack[8];
#pragma unroll
      for (int kk = 0; kk < 16; kk += 2) {
        int g0 = k0 + kb + kk, g1 = g0 + 1;
        float a = (g0 < K) ? bsrc[(long long)g0 * bstride] : 0.f;
        float c = (g1 < K) ? bsrc[(long long)g1 * bstride] : 0.f;
        pack[kk >> 1] = (unsigned)f2bf(a) | ((unsigned)f2bf(c) << 16);
      }
      *(uint4*)&Bs[bn * KPAD + kb]     = *(uint4*)&pack[0];
      *(uint4*)&Bs[bn * KPAD + kb + 8] = *(uint4*)&pack[4];
    }
    __syncthreads();
    // ---- MFMA: lane holds A[lm][kg*8+t], B[kg*8+t][lm], D row=kg*4+r col=lm ----
    {
      const int lk = kg * 8;
      short8v af[4], bfr[4];
#pragma unroll
      for (int mi = 0; mi < 4; ++mi)
        af[mi] = *(const short8v*)&As[(wr * 64 + mi * 16 + lm) * KPAD + lk];
#pragma unroll
      for (int nj = 0; nj < 4; ++nj)
        bfr[nj] = *(const short8v*)&Bs[(wc * 64 + nj * 16 + lm) * KPAD + lk];
#pragma unroll
      for (int mi = 0; mi < 4; ++mi)
#pragma unroll
        for (int nj = 0; nj < 4; ++nj)
          acc[mi][nj] = __builtin_amdgcn_mfma_f32_16x16x32_bf16(af[mi], bfr[nj], acc[mi][nj], 0, 0, 0);
    }
    __syncthreads();
  }

  const int rbase = m0 + wr * 64;
  const int cbase = n0 + wc * 64;

  if constexpr (MODE == 0 || MODE == 3) {
#pragma unroll
    for (int mi = 0; mi < 4; ++mi)
#pragma unroll
      for (int r = 0; r < 4; ++r) {
        int grow = rbase + mi * 16 + kg * 4 + r;
        if (grow >= M) continue;
#pragma unroll
        for (int nj = 0; nj < 4; ++nj) {
          int gcol = cbase + nj * 16 + lm;
          float t = acc[mi][nj][r] + (bias ? bias[gcol] : 0.f);
          float v;
          if constexpr (MODE == 3) v = fmaxf(ug[gcol] * t, 0.f);
          else v = do_relu ? fmaxf(t, 0.f) : t;
          C[(long long)grow * N + gcol] = v;
        }
      }
  } else if constexpr (MODE == 2) {
#pragma unroll
    for (int mi = 0; mi < 4; ++mi)
#pragma unroll
      for (int r = 0; r < 4; ++r) {
        int grow = rbase + mi * 16 + kg * 4 + r;
        if (grow >= M) continue;
        int gmg = rowbase + grow;
        int h = gmg / NNN, n = gmg - h * NNN;
        if (n == h) continue;               // diagonal pair removed
        long long orow = gmg - h - (n > h ? 1 : 0);
#pragma unroll
        for (int nj = 0; nj < 4; ++nj) {
          int gcol = cbase + nj * 16 + lm;
          float v = fmaxf(acc[mi][nj][r] + bias[gcol], 0.f);
          C[orow * 2048 + colofs + gcol] = v;
        }
      }
  } else if constexpr (MODE == 1) {
#pragma unroll
    for (int mi = 0; mi < 4; ++mi)
#pragma unroll
      for (int r = 0; r < 4; ++r) {
        float s = 0.f;
#pragma unroll
        for (int nj = 0; nj < 4; ++nj) {
          int gcol = cbase + nj * 16 + lm;
          float v = fmaxf(acc[mi][nj][r] + bias[gcol], 0.f);
          s = fmaf(v, wadj[gcol], s);
        }
#pragma unroll
        for (int off = 1; off < 16; off <<= 1) s += __shfl_xor(s, off);
        if (lm == 0) red2[wr * 64 + mi * 16 + kg * 4 + r][wc] = s;
      }
    __syncthreads();
    if (tid < BM) {
      int gm = m0 + tid;
      if (gm < M) part[(long long)gm * 8 + blockIdx.x] = red2[tid][0] + red2[tid][1];
    }
  }
}

// V[p_local,:] = relu((uh[h,:] + un[n,:]) * V[p_local,:]), global p = rowbase+p_local
__global__ __launch_bounds__(256) void tmul_k(float* __restrict__ V,
    const float* __restrict__ uh, const float* __restrict__ un, int rowbase)
{
  int pl = blockIdx.x;
  int pg = rowbase + pl;
  int h = pg / NNN, n = pg - h * NNN;
  const float* uhr = uh + (long long)h * NEC;
  const float* unr = un + (long long)n * NEC;
  float* Vr = V + (long long)pl * NEC;
  for (int j = threadIdx.x; j < NEC; j += 256) {
    float u = uhr[j] + unr[j];
    Vr[j] = fmaxf(u * Vr[j], 0.f);
  }
}

// tw[h,j] = sum_n soft[h,n] * relu(uO[n,j] * V[(h_l*384+n),j]),  h = h0 + h_l
__global__ __launch_bounds__(256) void tw_k(const float* __restrict__ V,
    const float* __restrict__ uO, const float* __restrict__ soft,
    float* __restrict__ tw, int h0)
{
  int hl = blockIdx.x;
  int h = h0 + hl;
  int j = blockIdx.y * 256 + threadIdx.x;
  const float* srow = soft + h * NNN;
  float s = 0.f;
  for (int n = 0; n < NNN; ++n) {
    float t = fmaxf(uO[(long long)n * NEC + j] * V[((long long)hl * NNN + n) * NEC + j], 0.f);
    s = fmaf(srow[n], t, s);
  }
  tw[(long long)h * NEC + j] = s;
}

// two[n,j] (+)= sum_{h_l<HPC} softT[n, h0+h_l] * relu(uS[h0+h_l,j] * V[(h_l*384+n),j])
__global__ __launch_bounds__(256) void two_k(const float* __restrict__ V,
    const float* __restrict__ uS, const float* __restrict__ softT,
    float* __restrict__ two, int h0, int accum)
{
  int n = blockIdx.x;
  int j = blockIdx.y * 256 + threadIdx.x;
  const float* srow = softT + n * NHH;
  float s = 0.f;
#pragma unroll
  for (int hl = 0; hl < HPC; ++hl) {
    int h = h0 + hl;
    float t = fmaxf(uS[(long long)h * NEC + j] * V[((long long)hl * NNN + n) * NEC + j], 0.f);
    s = fmaf(srow[h], t, s);
  }
  long long idx = (long long)n * NEC + j;
  two[idx] = accum ? (two[idx] + s) : s;
}

__global__ void adjfin_k(const float* __restrict__ part, const float* __restrict__ badj,
                         float* __restrict__ adj)
{
  int p = blockIdx.x * blockDim.x + threadIdx.x;
  if (p < NP) {
    float s = badj[0];
#pragma unroll
    for (int c = 0; c < 8; ++c) s += part[(long long)p * 8 + c];
    adj[p] = s;
  }
}

__global__ __launch_bounds__(64) void softmax_row_k(const float* __restrict__ adj,
                                                    float* __restrict__ soft)
{
  __shared__ float buf[NNN];
  int h = blockIdx.x, t = threadIdx.x;
  float mx = -1e30f;
  for (int n = t; n < NNN; n += 64) { float v = adj[h * NNN + n]; buf[n] = v; mx = fmaxf(mx, v); }
#pragma unroll
  for (int off = 32; off >= 1; off >>= 1) mx = fmaxf(mx, __shfl_xor(mx, off));
  float s = 0.f;
  for (int n = t; n < NNN; n += 64) { float e = expf(buf[n] - mx); buf[n] = e; s += e; }
#pragma unroll
  for (int off = 32; off >= 1; off >>= 1) s += __shfl_xor(s, off);
  float inv = 1.f / s;
  for (int n = t; n < NNN; n += 64) soft[h * NNN + n] = buf[n] * inv;
}

__global__ __launch_bounds__(64) void softmaxT_k(const float* __restrict__ adj,
                                                 float* __restrict__ softT)
{
  int n = blockIdx.x, t = threadIdx.x;
  float v = (t < NHH) ? adj[t * NNN + n] : -1e30f;
  float mx = v;
#pragma unroll
  for (int off = 32; off >= 1; off >>= 1) mx = fmaxf(mx, __shfl_xor(mx, off));
  float e = (t < NHH) ? expf(v - mx) : 0.f;
  float s = e;
#pragma unroll
  for (int off = 32; off >= 1; off >>= 1) s += __shfl_xor(s, off);
  if (t < NHH) softT[n * NHH + t] = e / s;
}

// out[r,:] = LN(x[r,:] + m[r,:]) * g + b
__global__ __launch_bounds__(256) void ln_k(const float* __restrict__ x, const float* __restrict__ m,
    const float* __restrict__ g, const float* __restrict__ b, float* __restrict__ out)
{
  int r = blockIdx.x, t = threadIdx.x;
  __shared__ float rs[4], rs2[4];
  const float* xr = x + (long long)r * NEC;
  const float* mr = m + (long long)r * NEC;
  float s = 0.f, s2 = 0.f;
  for (int j = t; j < NEC; j += 256) { float v = xr[j] + mr[j]; s += v; s2 = fmaf(v, v, s2); }
#pragma unroll
  for (int off = 32; off >= 1; off >>= 1) { s += __shfl_xor(s, off); s2 += __shfl_xor(s2, off); }
  if ((t & 63) == 0) { rs[t >> 6] = s; rs2[t >> 6] = s2; }
  __syncthreads();
  s = rs[0] + rs[1] + rs[2] + rs[3];
  s2 = rs2[0] + rs2[1] + rs2[2] + rs2[3];
  float mean = s * (1.f / NEC);
  float var = s2 * (1.f / NEC) - mean * mean;
  float rstd = rsqrtf(var + 1e-5f);
  float* o = out + (long long)r * NEC;
  for (int j = t; j < NEC; j += 256) {
    float v = xr[j] + mr[j];
    o[j] = (v - mean) * rstd * g[j] + b[j];
  }
}

__global__ __launch_bounds__(64) void gfeat_k(const float* __restrict__ feat3,
                                              float* __restrict__ gfeat)
{
  int ch = blockIdx.x, t = threadIdx.x;
  float s = 0.f;
  for (int i = t; i < 625; i += 64) s += feat3[ch * 625 + i];
#pragma unroll
  for (int off = 32; off >= 1; off >>= 1) s += __shfl_xor(s, off);
  if (t == 0) gfeat[ch] = s * (1.f / 625.f);
}

__global__ __launch_bounds__(256) void b3sum_k(const float* __restrict__ b3,
                                               float* __restrict__ out)
{
  int r = blockIdx.x * 256 + threadIdx.x;
  if (r < NEC) {
    float s = 0.f;
#pragma unroll
    for (int c = 0; c < 16; ++c) s += b3[c * NEC + r];
    out[r] = s;
  }
}

extern "C" void kernel_launch(void* const* d_in, const int* in_sizes, int n_in,
                              void* d_out, int out_size, void* d_ws, size_t ws_size,
                              hipStream_t stream)
{
  const float* box   = (const float*)d_in[0];
  const float* feat3 = (const float*)d_in[1];
  const float* sp36  = (const float*)d_in[2];
  const float* Wbh1  = (const float*)d_in[3];
  const float* bbh1  = (const float*)d_in[4];
  const float* Wbh2  = (const float*)d_in[5];
  const float* bbh2  = (const float*)d_in[6];
  const float* Wsp1  = (const float*)d_in[7];
  const float* bsp1  = (const float*)d_in[8];
  const float* Wsp2  = (const float*)d_in[9];
  const float* bsp2  = (const float*)d_in[10];
  const float* Wsp3  = (const float*)d_in[11];
  const float* bsp3  = (const float*)d_in[12];
  const float* Wadj  = (const float*)d_in[13];
  const float* badj  = (const float*)d_in[14];
  const float* A1W = (const float*)d_in[15]; const float* A1b = (const float*)d_in[16];
  const float* A2W = (const float*)d_in[17]; const float* A2b = (const float*)d_in[18];
  const float* A3W = (const float*)d_in[19]; const float* A3b = (const float*)d_in[20];
  const float* O1W = (const float*)d_in[21]; const float* O1b = (const float*)d_in[22];
  const float* O2W = (const float*)d_in[23]; const float* O2b = (const float*)d_in[24];
  const float* O3W = (const float*)d_in[25]; const float* O3b = (const float*)d_in[26];
  const float* S1W = (const float*)d_in[27]; const float* S1b = (const float*)d_in[28];
  const float* S2W = (const float*)d_in[29]; const float* S2b = (const float*)d_in[30];
  const float* S3W = (const float*)d_in[31]; const float* S3b = (const float*)d_in[32];
  const float* G1W = (const float*)d_in[33]; const float* G1b = (const float*)d_in[34];
  const float* G2W = (const float*)d_in[35]; const float* G2b = (const float*)d_in[36];
  const float* G3W = (const float*)d_in[37]; const float* G3b = (const float*)d_in[38];
  const float* gln_h = (const float*)d_in[39]; const float* bln_h = (const float*)d_in[40];
  const float* gln_o = (const float*)d_in[41]; const float* bln_o = (const float*)d_in[42];
  (void)in_sizes; (void)n_in; (void)out_size; (void)ws_size;

  float* w = (float*)d_ws;
  size_t off = 0;
  auto alloc = [&](size_t nelem) { float* p = w + off; off += nelem; return p; };
  float* SP    = alloc((size_t)NP * NEC);      // 75.5 MB, lives whole call
  float* Vc    = alloc((size_t)CHUNK * NEC);   // 9.4 MB per-chunk scratch
  float* s1c   = Vc;                            // aliases inside Vc (sp MLP staging)
  float* s2c   = Vc + (size_t)CHUNK * 128;
  float* node1 = alloc(384 * NEC);
  float* node  = alloc(384 * NEC);
  float* hnode1= alloc(48 * NEC);
  float* node2 = alloc(384 * NEC);
  float* uhA   = alloc(48 * NEC);
  float* unA   = alloc(384 * NEC);
  float* uO    = alloc(384 * NEC);
  float* uS    = alloc(48 * NEC);
  float* uh2   = alloc(48 * NEC);
  float* un2   = alloc(384 * NEC);
  float* uG    = alloc(NEC);
  float* gfeat = alloc(256);
  float* b3A = alloc(NEC); float* b3O = alloc(NEC); float* b3S = alloc(NEC); float* b3G = alloc(NEC);
  float* part  = alloc((size_t)NP * 16);
  float* adj   = alloc(NP);
  float* soft  = alloc(NP);
  float* softT = alloc(NP);
  float* twb   = alloc(48 * NEC);
  float* twob  = alloc(384 * NEC);
  float* m_h   = alloc(48 * NEC);
  float* m_o   = alloc(384 * NEC);

  auto gemm0 = [&](const float* A, const float* B, long long ldbB, float* C,
                   int M, int N, int K, const float* bias, int relu) {
    dim3 grid(N / BN, (M + BM - 1) / BM);
    hipLaunchKernelGGL((gemm_mfma<0>), grid, dim3(256), 0, stream,
                       A, B, ldbB, C, M, N, K, bias, relu,
                       (const float*)nullptr, (const float*)nullptr, (float*)nullptr, 0, 0);
  };

  gfeat_k<<<256, 64, 0, stream>>>(feat3, gfeat);
  b3sum_k<<<4, 256, 0, stream>>>(A3b, b3A);
  b3sum_k<<<4, 256, 0, stream>>>(O3b, b3O);
  b3sum_k<<<4, 256, 0, stream>>>(S3b, b3S);
  b3sum_k<<<4, 256, 0, stream>>>(G3b, b3G);

  // node MLP
  gemm0(box, Wbh1, 0, node1, 384, NEC, 12544, bbh1, 1);
  gemm0(node1, Wbh2, 0, node, 384, NEC, NEC, bbh2, 1);

  // spatial MLP, chunked through Vc staging
  for (int c = 0; c < NCH; ++c) {
    int rb = c * CHUNK;
    gemm0(sp36 + (long long)rb * 36, Wsp1, 0, s1c, CHUNK, 128, 36, bsp1, 1);
    gemm0(s1c, Wsp2, 0, s2c, CHUNK, 256, 128, bsp2, 1);
    gemm0(s2c, Wsp3, 0, SP + (long long)rb * NEC, CHUNK, NEC, 256, bsp3, 1);
  }

  // ---- adjacency head (A), chunked ----
  gemm0(node, A1W, 2048LL * 64, uhA, 48, NEC, NEC, A1b, 0);
  gemm0(node, A1W + 1024 * 64, 2048LL * 64, unA, 384, NEC, NEC, nullptr, 0);
  for (int c = 0; c < NCH; ++c) {
    int rb = c * CHUNK;
    gemm0(SP + (long long)rb * NEC, A2W, 1024LL * 64, Vc, CHUNK, NEC, NEC, A2b, 0);
    tmul_k<<<CHUNK, 256, 0, stream>>>(Vc, uhA, unA, rb);
    dim3 grid(8, CHUNK / BM);
    hipLaunchKernelGGL((gemm_mfma<1>), grid, dim3(256), 0, stream,
                       Vc, A3W, 0LL, (float*)nullptr, CHUNK, NEC, NEC, b3A, 1,
                       (const float*)nullptr, Wadj, part + (long long)rb * 8, 0, 0);
  }
  adjfin_k<<<(NP + 255) / 256, 256, 0, stream>>>(part, badj, adj);
  softmax_row_k<<<NHH, 64, 0, stream>>>(adj, soft);
  softmaxT_k<<<NNN, 64, 0, stream>>>(adj, softT);

  // ---- m_h (O head), chunked ----
  gemm0(node, O1W, 1024LL * 64, uO, 384, NEC, NEC, O1b, 0);
  for (int c = 0; c < NCH; ++c) {
    int rb = c * CHUNK;
    gemm0(SP + (long long)rb * NEC, O2W, 1024LL * 64, Vc, CHUNK, NEC, NEC, O2b, 0);
    tw_k<<<dim3(HPC, 4), 256, 0, stream>>>(Vc, uO, soft, twb, c * HPC);
  }
  gemm0(twb, O3W, 0, m_h, 48, NEC, NEC, b3O, 1);
  ln_k<<<NHH, 256, 0, stream>>>(node, m_h, gln_h, bln_h, hnode1);

  // ---- m_o (S head), chunked with accumulation ----
  gemm0(hnode1, S1W, 1024LL * 64, uS, 48, NEC, NEC, S1b, 0);
  for (int c = 0; c < NCH; ++c) {
    int rb = c * CHUNK;
    gemm0(SP + (long long)rb * NEC, S2W, 1024LL * 64, Vc, CHUNK, NEC, NEC, S2b, 0);
    two_k<<<dim3(NNN, 4), 256, 0, stream>>>(Vc, uS, softT, twob, c * HPC, c > 0);
  }
  gemm0(twob, S3W, 0, m_o, 384, NEC, NEC, b3S, 1);
  ln_k<<<NNN, 256, 0, stream>>>(node, m_o, gln_o, bln_o, node2);

  // ---- f_pair (A head on updated nodes), chunked ----
  gemm0(hnode1, A1W, 2048LL * 64, uh2, 48, NEC, NEC, A1b, 0);
  gemm0(node2, A1W + 1024 * 64, 2048LL * 64, un2, 384, NEC, NEC, nullptr, 0);
  for (int c = 0; c < NCH; ++c) {
    int rb = c * CHUNK;
    gemm0(SP + (long long)rb * NEC, A2W, 1024LL * 64, Vc, CHUNK, NEC, NEC, A2b, 0);
    tmul_k<<<CHUNK, 256, 0, stream>>>(Vc, uh2, un2, rb);
    dim3 grid(8, CHUNK / BM);
    hipLaunchKernelGGL((gemm_mfma<2>), grid, dim3(256), 0, stream,
                       Vc, A3W, 0LL, (float*)d_out, CHUNK, NEC, NEC, b3A, 1,
                       (const float*)nullptr, (const float*)nullptr, (float*)nullptr, 0, rb);
  }

  // ---- f_glob (G head), chunked ----
  {
    dim3 g1(NEC / BN, 1);
    hipLaunchKernelGGL((gemm_mfma<0>), g1, dim3(256), 0, stream,
                       gfeat, G1W, 256LL * 64, uG, 1, NEC, 256, G1b, 0,
                       (const float*)nullptr, (const float*)nullptr, (float*)nullptr, 0, 0);
  }
  for (int c = 0; c < NCH; ++c) {
    int rb = c * CHUNK;
    dim3 grid(8, CHUNK / BM);
    hipLaunchKernelGGL((gemm_mfma<3>), grid, dim3(256), 0, stream,
                       SP + (long long)rb * NEC, G2W, 1024LL * 64, Vc, CHUNK, NEC, NEC, G2b, 0,
                       uG, (const float*)nullptr, (float*)nullptr, 0, 0);
    hipLaunchKernelGGL((gemm_mfma<2>), grid, dim3(256), 0, stream,
                       Vc, G3W, 0LL, (float*)d_out, CHUNK, NEC, NEC, b3G, 1,
                       (const float*)nullptr, (const float*)nullptr, (float*)nullptr, 1024, rb);
  }
}

// Round 5
// 1604.432 us; speedup vs baseline: 7.9303x; 5.5018x over previous
//
#include <hip/hip_runtime.h>
#include <math.h>

#define NHH 48
#define NNN 384
#define NP  18432   // NHH*NNN
#define NEC 1024

#define BM 128
#define BN 128
#define BK 32
#define KPAD 40     // padded bf16 elems per LDS row

typedef __attribute__((ext_vector_type(8))) short short8v;   // 8 bf16 (4 VGPR)
typedef __attribute__((ext_vector_type(4))) float f32x4;     // MFMA acc

__device__ __forceinline__ unsigned short f2bf(float x) {
  unsigned int u = __float_as_uint(x);
  u += 0x7fffu + ((u >> 16) & 1u);   // RNE
  return (unsigned short)(u >> 16);
}
__device__ __forceinline__ float bf2f(unsigned short b) {
  return __uint_as_float(((unsigned)b) << 16);
}

// ---------------------------------------------------------------------------
// Unified bf16-MFMA GEMM. A: f32 (converted at staging) or bf16 (ABF16).
// B: f32 weights; ldbBlock==0 -> row-major [K,N], else column-block-64 head
// weights (block bx at B + bx*ldbBlock, elem [k*64 + (col&63)]).
// Split-K: kbeg = blockIdx.z*Ks, kend = min(K, kbeg+Ks). Non-split: Ks=K.
// MODE 0: C = maybe_relu(acc + bias)                (C f32 or bf16 per CBF16)
// MODE 1: part[grow*8+bx] = sum_j relu(acc+bias)*x1[j]        (adj partials)
// MODE 2: d_out[orow*2048 + colofs + j] = relu(acc+bias), skip diag pairs
// MODE 3: C = relu(x1[j] * (acc+bias))                        (G2 fused)
// MODE 4: C = relu((x1[row/384]+x2[row%384])[j] * (acc+bias)) (A2+tmul fused)
// MODE 5: part[(z*M+row)*N+j] = acc                           (split-K slice)
// ---------------------------------------------------------------------------
template<int MODE, int ABF16, int CBF16>
__global__ __launch_bounds__(256) void gemm_mfma(
    const void* __restrict__ Av, const float* __restrict__ B, long long ldbBlock,
    void* __restrict__ Cv, int M, int N, int K, int Ks,
    const float* __restrict__ bias, int do_relu,
    const float* __restrict__ x1, const float* __restrict__ x2,
    float* __restrict__ part, int colofs)
{
  __shared__ unsigned short As[BM * KPAD];
  __shared__ unsigned short Bs[BN * KPAD];
  __shared__ float red2[BM][2];

  const float* Af = (const float*)Av;
  const unsigned short* Ab = (const unsigned short*)Av;

  const int tid  = threadIdx.x;
  const int lane = tid & 63;
  const int wave = tid >> 6;
  const int wr = wave >> 1, wc = wave & 1;
  const int lm = lane & 15;
  const int kg = lane >> 4;
  const int m0 = blockIdx.y * BM, n0 = blockIdx.x * BN;
  const int kbeg = blockIdx.z * Ks;
  const int kend = min(K, kbeg + Ks);

  f32x4 acc[4][4];
#pragma unroll
  for (int i = 0; i < 4; ++i)
#pragma unroll
    for (int j = 0; j < 4; ++j)
      acc[i][j] = (f32x4){0.f, 0.f, 0.f, 0.f};

  const int bn = tid & 127;
  const int kb = (tid >> 7) * 16;
  const float* bsrc; long long bstride;
  {
    int gcol = n0 + bn;
    if (ldbBlock) { bsrc = B + (long long)(gcol >> 6) * ldbBlock + (gcol & 63); bstride = 64; }
    else          { bsrc = B + gcol; bstride = N; }
  }

  for (int k0 = kbeg; k0 < kend; k0 += BK) {
    // ---- stage A tile (BM x BK) ----
    if constexpr (ABF16) {
      int m = tid >> 1, kh = (tid & 1) * 16;
      int gm = m0 + m;
      uint4 p0 = {0,0,0,0}, p1 = {0,0,0,0};
      if (gm < M) {
        const uint4* s = (const uint4*)(Ab + (size_t)gm * K + k0 + kh);
        p0 = s[0]; p1 = s[1];
      }
      *(uint4*)&As[m * KPAD + kh]     = p0;
      *(uint4*)&As[m * KPAD + kh + 8] = p1;
    } else {
#pragma unroll
      for (int j = 0; j < 4; ++j) {
        int m = (tid >> 3) + j * 32;
        int k = (tid & 7) * 4;
        int gm = m0 + m, gk = k0 + k;
        float x0 = 0.f, x1v = 0.f, x2v = 0.f, x3 = 0.f;
        if (gm < M) {
          const float* src = Af + (long long)gm * K + gk;
          if (gk + 3 < K) { float4 v = *(const float4*)src; x0 = v.x; x1v = v.y; x2v = v.z; x3 = v.w; }
          else {
            if (gk     < K) x0  = src[0];
            if (gk + 1 < K) x1v = src[1];
            if (gk + 2 < K) x2v = src[2];
            if (gk + 3 < K) x3  = src[3];
          }
        }
        uint2 w2;
        w2.x = (unsigned)f2bf(x0)  | ((unsigned)f2bf(x1v) << 16);
        w2.y = (unsigned)f2bf(x2v) | ((unsigned)f2bf(x3)  << 16);
        *(uint2*)&As[m * KPAD + k] = w2;
      }
    }
    // ---- stage B tile (BK x BN) transposed into Bs[n][k] ----
    {
      unsigned pack[8];
#pragma unroll
      for (int kk = 0; kk < 16; kk += 2) {
        int g0 = k0 + kb + kk, g1 = g0 + 1;
        float a = (g0 < K) ? bsrc[(long long)g0 * bstride] : 0.f;
        float c = (g1 < K) ? bsrc[(long long)g1 * bstride] : 0.f;
        pack[kk >> 1] = (unsigned)f2bf(a) | ((unsigned)f2bf(c) << 16);
      }
      *(uint4*)&Bs[bn * KPAD + kb]     = *(uint4*)&pack[0];
      *(uint4*)&Bs[bn * KPAD + kb + 8] = *(uint4*)&pack[4];
    }
    __syncthreads();
    {
      const int lk = kg * 8;
      short8v af[4], bfr[4];
#pragma unroll
      for (int mi = 0; mi < 4; ++mi)
        af[mi] = *(const short8v*)&As[(wr * 64 + mi * 16 + lm) * KPAD + lk];
#pragma unroll
      for (int nj = 0; nj < 4; ++nj)
        bfr[nj] = *(const short8v*)&Bs[(wc * 64 + nj * 16 + lm) * KPAD + lk];
#pragma unroll
      for (int mi = 0; mi < 4; ++mi)
#pragma unroll
        for (int nj = 0; nj < 4; ++nj)
          acc[mi][nj] = __builtin_amdgcn_mfma_f32_16x16x32_bf16(af[mi], bfr[nj], acc[mi][nj], 0, 0, 0);
    }
    __syncthreads();
  }

  const int rbase = m0 + wr * 64;
  const int cbase = n0 + wc * 64;

  if constexpr (MODE == 0 || MODE == 3 || MODE == 4) {
#pragma unroll
    for (int mi = 0; mi < 4; ++mi)
#pragma unroll
      for (int r = 0; r < 4; ++r) {
        int grow = rbase + mi * 16 + kg * 4 + r;
        if (grow >= M) continue;
        int h = 0, n = 0;
        if constexpr (MODE == 4) { h = grow / NNN; n = grow - h * NNN; }
#pragma unroll
        for (int nj = 0; nj < 4; ++nj) {
          int gcol = cbase + nj * 16 + lm;
          float t = acc[mi][nj][r] + (bias ? bias[gcol] : 0.f);
          float v;
          if constexpr (MODE == 3)      v = fmaxf(x1[gcol] * t, 0.f);
          else if constexpr (MODE == 4) v = fmaxf((x1[(size_t)h * NEC + gcol] + x2[(size_t)n * NEC + gcol]) * t, 0.f);
          else                          v = do_relu ? fmaxf(t, 0.f) : t;
          size_t idx = (size_t)grow * N + gcol;
          if constexpr (CBF16) ((unsigned short*)Cv)[idx] = f2bf(v);
          else                 ((float*)Cv)[idx] = v;
        }
      }
  } else if constexpr (MODE == 5) {
    size_t zofs = (size_t)blockIdx.z * M;
#pragma unroll
    for (int mi = 0; mi < 4; ++mi)
#pragma unroll
      for (int r = 0; r < 4; ++r) {
        int grow = rbase + mi * 16 + kg * 4 + r;
        if (grow >= M) continue;
#pragma unroll
        for (int nj = 0; nj < 4; ++nj) {
          int gcol = cbase + nj * 16 + lm;
          part[(zofs + grow) * N + gcol] = acc[mi][nj][r];
        }
      }
  } else if constexpr (MODE == 2) {
#pragma unroll
    for (int mi = 0; mi < 4; ++mi)
#pragma unroll
      for (int r = 0; r < 4; ++r) {
        int grow = rbase + mi * 16 + kg * 4 + r;
        if (grow >= M) continue;
        int h = grow / NNN, n = grow - h * NNN;
        if (n == h) continue;
        long long orow = grow - h - (n > h ? 1 : 0);
#pragma unroll
        for (int nj = 0; nj < 4; ++nj) {
          int gcol = cbase + nj * 16 + lm;
          float v = fmaxf(acc[mi][nj][r] + bias[gcol], 0.f);
          ((float*)Cv)[orow * 2048 + colofs + gcol] = v;
        }
      }
  } else if constexpr (MODE == 1) {
#pragma unroll
    for (int mi = 0; mi < 4; ++mi)
#pragma unroll
      for (int r = 0; r < 4; ++r) {
        float s = 0.f;
#pragma unroll
        for (int nj = 0; nj < 4; ++nj) {
          int gcol = cbase + nj * 16 + lm;
          float v = fmaxf(acc[mi][nj][r] + bias[gcol], 0.f);
          s = fmaf(v, x1[gcol], s);
        }
#pragma unroll
        for (int off = 1; off < 16; off <<= 1) s += __shfl_xor(s, off);
        if (lm == 0) red2[wr * 64 + mi * 16 + kg * 4 + r][wc] = s;
      }
    __syncthreads();
    if (tid < BM) {
      int gm = m0 + tid;
      if (gm < M) part[(size_t)gm * 8 + blockIdx.x] = red2[tid][0] + red2[tid][1];
    }
  }
}

// C[i] = maybe_relu(sum_z P[z*MN+i] + bias[i%N])
__global__ __launch_bounds__(256) void ksum_k(const float* __restrict__ P,
    const float* __restrict__ bias, int do_relu, float* __restrict__ C,
    int MN, int N, int S)
{
  int i = blockIdx.x * 256 + threadIdx.x;
  if (i < MN) {
    float s = 0.f;
    for (int z = 0; z < S; ++z) s += P[(size_t)z * MN + i];
    if (bias) s += bias[i % N];
    C[i] = do_relu ? fmaxf(s, 0.f) : s;
  }
}

// tw[h,j] = sum_n soft[h,n] * relu(uO[n,j] * V[(h*384+n),j])   (V bf16)
__global__ __launch_bounds__(256) void tw_k(const unsigned short* __restrict__ V,
    const float* __restrict__ uO, const float* __restrict__ soft, float* __restrict__ tw)
{
  int h = blockIdx.x;
  int j = blockIdx.y * 256 + threadIdx.x;
  const float* srow = soft + h * NNN;
  float s = 0.f;
  for (int n = 0; n < NNN; ++n) {
    float v = bf2f(V[((size_t)h * NNN + n) * NEC + j]);
    float t = fmaxf(uO[(size_t)n * NEC + j] * v, 0.f);
    s = fmaf(srow[n], t, s);
  }
  tw[(size_t)h * NEC + j] = s;
}

// two[n,j] = sum_h softT[n,h] * relu(uS[h,j] * V[(h*384+n),j])   (V bf16)
__global__ __launch_bounds__(256) void two_k(const unsigned short* __restrict__ V,
    const float* __restrict__ uS, const float* __restrict__ softT, float* __restrict__ two)
{
  int n = blockIdx.x;
  int j = blockIdx.y * 256 + threadIdx.x;
  const float* srow = softT + n * NHH;
  float s = 0.f;
#pragma unroll 8
  for (int h = 0; h < NHH; ++h) {
    float v = bf2f(V[((size_t)h * NNN + n) * NEC + j]);
    float t = fmaxf(uS[(size_t)h * NEC + j] * v, 0.f);
    s = fmaf(srow[h], t, s);
  }
  two[(size_t)n * NEC + j] = s;
}

__global__ void adjfin_k(const float* __restrict__ part, const float* __restrict__ badj,
                         float* __restrict__ adj)
{
  int p = blockIdx.x * blockDim.x + threadIdx.x;
  if (p < NP) {
    float s = badj[0];
#pragma unroll
    for (int c = 0; c < 8; ++c) s += part[(size_t)p * 8 + c];
    adj[p] = s;
  }
}

__global__ __launch_bounds__(64) void softmax_row_k(const float* __restrict__ adj,
                                                    float* __restrict__ soft)
{
  __shared__ float buf[NNN];
  int h = blockIdx.x, t = threadIdx.x;
  float mx = -1e30f;
  for (int n = t; n < NNN; n += 64) { float v = adj[h * NNN + n]; buf[n] = v; mx = fmaxf(mx, v); }
#pragma unroll
  for (int off = 32; off >= 1; off >>= 1) mx = fmaxf(mx, __shfl_xor(mx, off));
  float s = 0.f;
  for (int n = t; n < NNN; n += 64) { float e = expf(buf[n] - mx); buf[n] = e; s += e; }
#pragma unroll
  for (int off = 32; off >= 1; off >>= 1) s += __shfl_xor(s, off);
  float inv = 1.f / s;
  for (int n = t; n < NNN; n += 64) soft[h * NNN + n] = buf[n] * inv;
}

__global__ __launch_bounds__(64) void softmaxT_k(const float* __restrict__ adj,
                                                 float* __restrict__ softT)
{
  int n = blockIdx.x, t = threadIdx.x;
  float v = (t < NHH) ? adj[t * NNN + n] : -1e30f;
  float mx = v;
#pragma unroll
  for (int off = 32; off >= 1; off >>= 1) mx = fmaxf(mx, __shfl_xor(mx, off));
  float e = (t < NHH) ? expf(v - mx) : 0.f;
  float s = e;
#pragma unroll
  for (int off = 32; off >= 1; off >>= 1) s += __shfl_xor(s, off);
  if (t < NHH) softT[n * NHH + t] = e / s;
}

__global__ __launch_bounds__(256) void ln_k(const float* __restrict__ x, const float* __restrict__ m,
    const float* __restrict__ g, const float* __restrict__ b, float* __restrict__ out)
{
  int r = blockIdx.x, t = threadIdx.x;
  __shared__ float rs[4], rs2[4];
  const float* xr = x + (size_t)r * NEC;
  const float* mr = m + (size_t)r * NEC;
  float s = 0.f, s2 = 0.f;
  for (int j = t; j < NEC; j += 256) { float v = xr[j] + mr[j]; s += v; s2 = fmaf(v, v, s2); }
#pragma unroll
  for (int off = 32; off >= 1; off >>= 1) { s += __shfl_xor(s, off); s2 += __shfl_xor(s2, off); }
  if ((t & 63) == 0) { rs[t >> 6] = s; rs2[t >> 6] = s2; }
  __syncthreads();
  s = rs[0] + rs[1] + rs[2] + rs[3];
  s2 = rs2[0] + rs2[1] + rs2[2] + rs2[3];
  float mean = s * (1.f / NEC);
  float var = s2 * (1.f / NEC) - mean * mean;
  float rstd = rsqrtf(var + 1e-5f);
  float* o = out + (size_t)r * NEC;
  for (int j = t; j < NEC; j += 256) {
    float v = xr[j] + mr[j];
    o[j] = (v - mean) * rstd * g[j] + b[j];
  }
}

__global__ __launch_bounds__(64) void gfeat_k(const float* __restrict__ feat3,
                                              float* __restrict__ gfeat)
{
  int ch = blockIdx.x, t = threadIdx.x;
  float s = 0.f;
  for (int i = t; i < 625; i += 64) s += feat3[ch * 625 + i];
#pragma unroll
  for (int off = 32; off >= 1; off >>= 1) s += __shfl_xor(s, off);
  if (t == 0) gfeat[ch] = s * (1.f / 625.f);
}

__global__ __launch_bounds__(256) void b3sum_k(const float* __restrict__ b3,
                                               float* __restrict__ out)
{
  int r = blockIdx.x * 256 + threadIdx.x;
  if (r < NEC) {
    float s = 0.f;
#pragma unroll
    for (int c = 0; c < 16; ++c) s += b3[c * NEC + r];
    out[r] = s;
  }
}

extern "C" void kernel_launch(void* const* d_in, const int* in_sizes, int n_in,
                              void* d_out, int out_size, void* d_ws, size_t ws_size,
                              hipStream_t stream)
{
  const float* box   = (const float*)d_in[0];
  const float* feat3 = (const float*)d_in[1];
  const float* sp36  = (const float*)d_in[2];
  const float* Wbh1  = (const float*)d_in[3];
  const float* bbh1  = (const float*)d_in[4];
  const float* Wbh2  = (const float*)d_in[5];
  const float* bbh2  = (const float*)d_in[6];
  const float* Wsp1  = (const float*)d_in[7];
  const float* bsp1  = (const float*)d_in[8];
  const float* Wsp2  = (const float*)d_in[9];
  const float* bsp2  = (const float*)d_in[10];
  const float* Wsp3  = (const float*)d_in[11];
  const float* bsp3  = (const float*)d_in[12];
  const float* Wadj  = (const float*)d_in[13];
  const float* badj  = (const float*)d_in[14];
  const float* A1W = (const float*)d_in[15]; const float* A1b = (const float*)d_in[16];
  const float* A2W = (const float*)d_in[17]; const float* A2b = (const float*)d_in[18];
  const float* A3W = (const float*)d_in[19]; const float* A3b = (const float*)d_in[20];
  const float* O1W = (const float*)d_in[21]; const float* O1b = (const float*)d_in[22];
  const float* O2W = (const float*)d_in[23]; const float* O2b = (const float*)d_in[24];
  const float* O3W = (const float*)d_in[25]; const float* O3b = (const float*)d_in[26];
  const float* S1W = (const float*)d_in[27]; const float* S1b = (const float*)d_in[28];
  const float* S2W = (const float*)d_in[29]; const float* S2b = (const float*)d_in[30];
  const float* S3W = (const float*)d_in[31]; const float* S3b = (const float*)d_in[32];
  const float* G1W = (const float*)d_in[33]; const float* G1b = (const float*)d_in[34];
  const float* G2W = (const float*)d_in[35]; const float* G2b = (const float*)d_in[36];
  const float* G3W = (const float*)d_in[37]; const float* G3b = (const float*)d_in[38];
  const float* gln_h = (const float*)d_in[39]; const float* bln_h = (const float*)d_in[40];
  const float* gln_o = (const float*)d_in[41]; const float* bln_o = (const float*)d_in[42];
  (void)in_sizes; (void)n_in; (void)out_size; (void)ws_size;

  // ---- workspace carve (~90 MB) ----
  char* base = (char*)d_ws;
  unsigned short* Vb  = (unsigned short*)base;                  // NP*NEC bf16 (37.7 MB)
  float* partial      = (float*)base;                           // alias: split-K partials (<=12.6 MB)
  unsigned short* s1  = Vb;                                     // alias: sp MLP stage 1 (NP*128)
  unsigned short* s2  = Vb + (size_t)NP * 128;                  // alias: sp MLP stage 2 (NP*256)
  unsigned short* SPb = (unsigned short*)(base + (size_t)NP * NEC * 2);  // NP*NEC bf16
  float* f = (float*)(base + (size_t)NP * NEC * 4);
  size_t off = 0;
  auto alloc = [&](size_t n) { float* p = f + off; off += n; return p; };
  float* node1 = alloc(384 * NEC);
  float* node  = alloc(384 * NEC);
  float* hnode1= alloc(48 * NEC);
  float* node2 = alloc(384 * NEC);
  float* uhA   = alloc(48 * NEC);
  float* unA   = alloc(384 * NEC);
  float* uO    = alloc(384 * NEC);
  float* uS    = alloc(48 * NEC);
  float* uh2   = alloc(48 * NEC);
  float* un2   = alloc(384 * NEC);
  float* uG    = alloc(NEC);
  float* gfeat = alloc(256);
  float* b3A = alloc(NEC); float* b3O = alloc(NEC); float* b3S = alloc(NEC); float* b3G = alloc(NEC);
  float* part  = alloc((size_t)NP * 8);
  float* adj   = alloc(NP);
  float* soft  = alloc(NP);
  float* softT = alloc(NP);
  float* twb   = alloc(48 * NEC);
  float* twob  = alloc(384 * NEC);
  float* m_h   = alloc(48 * NEC);
  float* m_o   = alloc(384 * NEC);

  // split-K f32 GEMM: MODE5 slices + ksum reduce (partial aliases Vb; only
  // legal when V is dead -- all call sites verified sequential-safe)
  auto gS = [&](const float* A, const float* B, long long lb, float* C,
                int M, int N, int K, const float* bias, int relu, int S) {
    int Ks = ((K + S * BK - 1) / (S * BK)) * BK;
    dim3 grid(N / BN, (M + BM - 1) / BM, S);
    hipLaunchKernelGGL((gemm_mfma<5, 0, 0>), grid, dim3(256), 0, stream,
                       A, B, lb, nullptr, M, N, K, Ks, nullptr, 0,
                       nullptr, nullptr, partial, 0);
    int MN = M * N;
    hipLaunchKernelGGL(ksum_k, dim3((MN + 255) / 256), dim3(256), 0, stream,
                       partial, bias, relu, C, MN, N, S);
  };

  gfeat_k<<<256, 64, 0, stream>>>(feat3, gfeat);
  b3sum_k<<<4, 256, 0, stream>>>(A3b, b3A);
  b3sum_k<<<4, 256, 0, stream>>>(O3b, b3O);
  b3sum_k<<<4, 256, 0, stream>>>(S3b, b3S);
  b3sum_k<<<4, 256, 0, stream>>>(G3b, b3G);

  // node MLP (split-K; partial aliases Vb, dead here)
  gS(box,   Wbh1, 0, node1, 384, NEC, 12544, bbh1, 1, 8);
  gS(node1, Wbh2, 0, node,  384, NEC, NEC,   bbh2, 1, 8);

  // spatial MLP -> SPb (bf16), staging s1/s2 alias Vb
  {
    dim3 g1(1, NP / BM); dim3 g2(2, NP / BM); dim3 g3(8, NP / BM);
    hipLaunchKernelGGL((gemm_mfma<0, 0, 1>), g1, dim3(256), 0, stream,
                       sp36, Wsp1, 0LL, s1, NP, 128, 36, 36, bsp1, 1, nullptr, nullptr, nullptr, 0);
    hipLaunchKernelGGL((gemm_mfma<0, 1, 1>), g2, dim3(256), 0, stream,
                       s1, Wsp2, 0LL, s2, NP, 256, 128, 128, bsp2, 1, nullptr, nullptr, nullptr, 0);
    hipLaunchKernelGGL((gemm_mfma<0, 1, 1>), g3, dim3(256), 0, stream,
                       s2, Wsp3, 0LL, SPb, NP, NEC, 256, 256, bsp3, 1, nullptr, nullptr, nullptr, 0);
  }

  dim3 gBig(8, NP / BM);

  // ---- adjacency head ----
  gS(node, A1W,             2048LL * 64, uhA, 48,  NEC, NEC, A1b,    0, 8);
  gS(node, A1W + 1024 * 64, 2048LL * 64, unA, 384, NEC, NEC, nullptr, 0, 8);
  hipLaunchKernelGGL((gemm_mfma<4, 1, 1>), gBig, dim3(256), 0, stream,   // V = relu((uh+un)*(SP@A2W+b2))
                     SPb, A2W, 1024LL * 64, Vb, NP, NEC, NEC, NEC, A2b, 0, uhA, unA, nullptr, 0);
  hipLaunchKernelGGL((gemm_mfma<1, 1, 0>), gBig, dim3(256), 0, stream,   // adj partials
                     Vb, A3W, 0LL, nullptr, NP, NEC, NEC, NEC, b3A, 1, Wadj, nullptr, part, 0);
  adjfin_k<<<(NP + 255) / 256, 256, 0, stream>>>(part, badj, adj);
  softmax_row_k<<<NHH, 64, 0, stream>>>(adj, soft);
  softmaxT_k<<<NNN, 64, 0, stream>>>(adj, softT);

  // ---- m_h (O head) ----
  gS(node, O1W, 1024LL * 64, uO, 384, NEC, NEC, O1b, 0, 8);
  hipLaunchKernelGGL((gemm_mfma<0, 1, 1>), gBig, dim3(256), 0, stream,   // vO
                     SPb, O2W, 1024LL * 64, Vb, NP, NEC, NEC, NEC, O2b, 0, nullptr, nullptr, nullptr, 0);
  tw_k<<<dim3(NHH, 4), 256, 0, stream>>>(Vb, uO, soft, twb);
  gS(twb, O3W, 0, m_h, 48, NEC, NEC, b3O, 1, 8);
  ln_k<<<NHH, 256, 0, stream>>>(node, m_h, gln_h, bln_h, hnode1);

  // ---- m_o (S head) ----
  gS(hnode1, S1W, 1024LL * 64, uS, 48, NEC, NEC, S1b, 0, 8);
  hipLaunchKernelGGL((gemm_mfma<0, 1, 1>), gBig, dim3(256), 0, stream,   // vS
                     SPb, S2W, 1024LL * 64, Vb, NP, NEC, NEC, NEC, S2b, 0, nullptr, nullptr, nullptr, 0);
  two_k<<<dim3(NNN, 4), 256, 0, stream>>>(Vb, uS, softT, twob);
  gS(twob, S3W, 0, m_o, 384, NEC, NEC, b3S, 1, 8);
  ln_k<<<NNN, 256, 0, stream>>>(node, m_o, gln_o, bln_o, node2);

  // ---- f_pair ----
  gS(hnode1, A1W,             2048LL * 64, uh2, 48,  NEC, NEC, A1b,    0, 8);
  gS(node2,  A1W + 1024 * 64, 2048LL * 64, un2, 384, NEC, NEC, nullptr, 0, 8);
  hipLaunchKernelGGL((gemm_mfma<4, 1, 1>), gBig, dim3(256), 0, stream,
                     SPb, A2W, 1024LL * 64, Vb, NP, NEC, NEC, NEC, A2b, 0, uh2, un2, nullptr, 0);
  hipLaunchKernelGGL((gemm_mfma<2, 1, 0>), gBig, dim3(256), 0, stream,
                     Vb, A3W, 0LL, (float*)d_out, NP, NEC, NEC, NEC, b3A, 1, nullptr, nullptr, nullptr, 0);

  // ---- f_glob ----
  {
    dim3 g1(8, 1);
    hipLaunchKernelGGL((gemm_mfma<0, 0, 0>), g1, dim3(256), 0, stream,
                       gfeat, G1W, 256LL * 64, uG, 1, NEC, 256, 256, G1b, 0, nullptr, nullptr, nullptr, 0);
  }
  hipLaunchKernelGGL((gemm_mfma<3, 1, 1>), gBig, dim3(256), 0, stream,   // V = relu(ug*(SP@G2W+b2))
                     SPb, G2W, 1024LL * 64, Vb, NP, NEC, NEC, NEC, G2b, 0, uG, nullptr, nullptr, 0);
  hipLaunchKernelGGL((gemm_mfma<2, 1, 0>), gBig, dim3(256), 0, stream,
                     Vb, G3W, 0LL, (float*)d_out, NP, NEC, NEC, NEC, b3G, 1, nullptr, nullptr, nullptr, 1024);
}

// Round 6
// 1230.203 us; speedup vs baseline: 10.3427x; 1.3042x over previous
//
#include <hip/hip_runtime.h>
#include <math.h>

#define NHH 48
#define NNN 384
#define NP  18432   // NHH*NNN
#define NEC 1024

#define BM 128
#define BN 128
#define BK 32
#define KPAD 40     // padded bf16 elems per LDS row

typedef __attribute__((ext_vector_type(8))) short short8v;   // 8 bf16 (4 VGPR)
typedef __attribute__((ext_vector_type(4))) float f32x4;     // MFMA acc

__device__ __forceinline__ unsigned short f2bf(float x) {
  unsigned int u = __float_as_uint(x);
  u += 0x7fffu + ((u >> 16) & 1u);   // RNE
  return (unsigned short)(u >> 16);
}
__device__ __forceinline__ float bf2f(unsigned short b) {
  return __uint_as_float(((unsigned)b) << 16);
}

// ---------------------------------------------------------------------------
// Weight pre-convert: f32 -> bf16, output transposed to [N][K].
// blocked=1: input head-blocked (16,K,64) (col c lives at in[(c>>6... )]).
// blocked=0: input row-major [K,N].
// LDS-tiled 64x64 transpose, both sides coalesced.
// ---------------------------------------------------------------------------
__global__ __launch_bounds__(256) void convw_k(const float* __restrict__ in,
    unsigned short* __restrict__ out, int K, int N, int blocked)
{
  __shared__ float t[64][65];
  int kb = blockIdx.x * 64, nb = blockIdx.y * 64;
  const float* src; size_t stride;
  if (blocked) { src = in + (size_t)(nb >> 6) * K * 64; stride = 64; }
  else         { src = in + nb; stride = N; }
  for (int i = threadIdx.x; i < 64 * 64; i += 256) {
    int k = i >> 6, d = i & 63;                 // read along n: coalesced
    t[d][k] = src[(size_t)(kb + k) * stride + d];
  }
  __syncthreads();
  for (int i = threadIdx.x; i < 64 * 64; i += 256) {
    int d = i >> 6, k = i & 63;                 // write along k: coalesced
    out[(size_t)(nb + d) * K + kb + k] = f2bf(t[d][k]);
  }
}

// ---------------------------------------------------------------------------
// Unified bf16-MFMA GEMM. A: f32 (converted at staging) or bf16 (ABF16).
// B: BBF16=1 -> pre-transposed bf16 [N][K]; BBF16=0 -> f32, ldbBlock==0
// row-major [K,N] else column-block-64 head weights.
// swz=1 (requires grid exactly (8,144)): XCD-bijective remap so the 8
// x-blocks sharing an A-row-panel land on one XCD (L2 locality).
// MODE 0: C = maybe_relu(acc + bias)
// MODE 1: part[grow*8+bx] = sum_j relu(acc+bias)*x1[j]        (adj partials)
// MODE 2: d_out[orow*2048 + colofs + j] = relu(acc+bias), skip diag pairs
// MODE 3: C = relu(x1[j] * (acc+bias))                        (G2 fused)
// MODE 4: C = relu((x1[row/384]+x2[row%384])[j] * (acc+bias)) (A2+tmul fused)
// MODE 5: part[(z*M+row)*N+j] = acc                           (split-K slice)
// ---------------------------------------------------------------------------
template<int MODE, int ABF16, int BBF16, int CBF16>
__global__ __launch_bounds__(256) void gemm_mfma(
    const void* __restrict__ Av, const void* __restrict__ Bv, long long ldbBlock,
    void* __restrict__ Cv, int M, int N, int K, int Ks,
    const float* __restrict__ bias, int do_relu,
    const float* __restrict__ x1, const float* __restrict__ x2,
    float* __restrict__ part, int colofs, int swz)
{
  __shared__ unsigned short As[BM * KPAD];
  __shared__ unsigned short Bs[BN * KPAD];
  __shared__ float red2[BM][2];

  const float* Af = (const float*)Av;
  const unsigned short* Ab = (const unsigned short*)Av;
  const float* Bf = (const float*)Bv;
  const unsigned short* Bb = (const unsigned short*)Bv;

  const int tid  = threadIdx.x;
  const int lane = tid & 63;
  const int wave = tid >> 6;
  const int wr = wave >> 1, wc = wave & 1;
  const int lm = lane & 15;
  const int kg = lane >> 4;

  int bx = blockIdx.x, by = blockIdx.y;
  if (swz) {                    // grid must be (8,144)
    int L = by * 8 + bx;
    int r = L & 7, q = L >> 3;  // q in 0..143
    bx = q / 18;
    by = r + 8 * (q - bx * 18);
  }
  const int m0 = by * BM, n0 = bx * BN;
  const int kbeg = blockIdx.z * Ks;
  const int kend = min(K, kbeg + Ks);

  f32x4 acc[4][4];
#pragma unroll
  for (int i = 0; i < 4; ++i)
#pragma unroll
    for (int j = 0; j < 4; ++j)
      acc[i][j] = (f32x4){0.f, 0.f, 0.f, 0.f};

  // f32-B staging precompute
  const int bn = tid & 127;
  const int kb = (tid >> 7) * 16;
  const float* bsrc = nullptr; long long bstride = 0;
  if constexpr (!BBF16) {
    int gcol = n0 + bn;
    if (ldbBlock) { bsrc = Bf + (long long)(gcol >> 6) * ldbBlock + (gcol & 63); bstride = 64; }
    else          { bsrc = Bf + gcol; bstride = N; }
  }

  for (int k0 = kbeg; k0 < kend; k0 += BK) {
    // ---- stage A tile (BM x BK) ----
    if constexpr (ABF16) {
      int m = tid >> 1, kh = (tid & 1) * 16;
      int gm = m0 + m;
      uint4 p0 = {0,0,0,0}, p1 = {0,0,0,0};
      if (gm < M) {
        const uint4* s = (const uint4*)(Ab + (size_t)gm * K + k0 + kh);
        p0 = s[0]; p1 = s[1];
      }
      *(uint4*)&As[m * KPAD + kh]     = p0;
      *(uint4*)&As[m * KPAD + kh + 8] = p1;
    } else {
#pragma unroll
      for (int j = 0; j < 4; ++j) {
        int m = (tid >> 3) + j * 32;
        int k = (tid & 7) * 4;
        int gm = m0 + m, gk = k0 + k;
        float x0 = 0.f, x1v = 0.f, x2v = 0.f, x3 = 0.f;
        if (gm < M) {
          const float* src = Af + (long long)gm * K + gk;
          if (gk + 3 < K) { float4 v = *(const float4*)src; x0 = v.x; x1v = v.y; x2v = v.z; x3 = v.w; }
          else {
            if (gk     < K) x0  = src[0];
            if (gk + 1 < K) x1v = src[1];
            if (gk + 2 < K) x2v = src[2];
            if (gk + 3 < K) x3  = src[3];
          }
        }
        uint2 w2;
        w2.x = (unsigned)f2bf(x0)  | ((unsigned)f2bf(x1v) << 16);
        w2.y = (unsigned)f2bf(x2v) | ((unsigned)f2bf(x3)  << 16);
        *(uint2*)&As[m * KPAD + k] = w2;
      }
    }
    // ---- stage B tile into Bs[n][k] ----
    if constexpr (BBF16) {
      int nrow = tid >> 1, kh = (tid & 1) * 16;
      const uint4* s = (const uint4*)(Bb + (size_t)(n0 + nrow) * K + k0 + kh);
      *(uint4*)&Bs[nrow * KPAD + kh]     = s[0];
      *(uint4*)&Bs[nrow * KPAD + kh + 8] = s[1];
    } else {
      unsigned pack[8];
#pragma unroll
      for (int kk = 0; kk < 16; kk += 2) {
        int g0 = k0 + kb + kk, g1 = g0 + 1;
        float a = (g0 < K) ? bsrc[(long long)g0 * bstride] : 0.f;
        float c = (g1 < K) ? bsrc[(long long)g1 * bstride] : 0.f;
        pack[kk >> 1] = (unsigned)f2bf(a) | ((unsigned)f2bf(c) << 16);
      }
      *(uint4*)&Bs[bn * KPAD + kb]     = *(uint4*)&pack[0];
      *(uint4*)&Bs[bn * KPAD + kb + 8] = *(uint4*)&pack[4];
    }
    __syncthreads();
    {
      const int lk = kg * 8;
      short8v af[4], bfr[4];
#pragma unroll
      for (int mi = 0; mi < 4; ++mi)
        af[mi] = *(const short8v*)&As[(wr * 64 + mi * 16 + lm) * KPAD + lk];
#pragma unroll
      for (int nj = 0; nj < 4; ++nj)
        bfr[nj] = *(const short8v*)&Bs[(wc * 64 + nj * 16 + lm) * KPAD + lk];
#pragma unroll
      for (int mi = 0; mi < 4; ++mi)
#pragma unroll
        for (int nj = 0; nj < 4; ++nj)
          acc[mi][nj] = __builtin_amdgcn_mfma_f32_16x16x32_bf16(af[mi], bfr[nj], acc[mi][nj], 0, 0, 0);
    }
    __syncthreads();
  }

  const int rbase = m0 + wr * 64;
  const int cbase = n0 + wc * 64;

  if constexpr (MODE == 0 || MODE == 3 || MODE == 4) {
#pragma unroll
    for (int mi = 0; mi < 4; ++mi)
#pragma unroll
      for (int r = 0; r < 4; ++r) {
        int grow = rbase + mi * 16 + kg * 4 + r;
        if (grow >= M) continue;
        int h = 0, n = 0;
        if constexpr (MODE == 4) { h = grow / NNN; n = grow - h * NNN; }
#pragma unroll
        for (int nj = 0; nj < 4; ++nj) {
          int gcol = cbase + nj * 16 + lm;
          float t = acc[mi][nj][r] + (bias ? bias[gcol] : 0.f);
          float v;
          if constexpr (MODE == 3)      v = fmaxf(x1[gcol] * t, 0.f);
          else if constexpr (MODE == 4) v = fmaxf((x1[(size_t)h * NEC + gcol] + x2[(size_t)n * NEC + gcol]) * t, 0.f);
          else                          v = do_relu ? fmaxf(t, 0.f) : t;
          size_t idx = (size_t)grow * N + gcol;
          if constexpr (CBF16) ((unsigned short*)Cv)[idx] = f2bf(v);
          else                 ((float*)Cv)[idx] = v;
        }
      }
  } else if constexpr (MODE == 5) {
    size_t zofs = (size_t)blockIdx.z * M;
#pragma unroll
    for (int mi = 0; mi < 4; ++mi)
#pragma unroll
      for (int r = 0; r < 4; ++r) {
        int grow = rbase + mi * 16 + kg * 4 + r;
        if (grow >= M) continue;
#pragma unroll
        for (int nj = 0; nj < 4; ++nj) {
          int gcol = cbase + nj * 16 + lm;
          part[(zofs + grow) * N + gcol] = acc[mi][nj][r];
        }
      }
  } else if constexpr (MODE == 2) {
#pragma unroll
    for (int mi = 0; mi < 4; ++mi)
#pragma unroll
      for (int r = 0; r < 4; ++r) {
        int grow = rbase + mi * 16 + kg * 4 + r;
        if (grow >= M) continue;
        int h = grow / NNN, n = grow - h * NNN;
        if (n == h) continue;
        long long orow = grow - h - (n > h ? 1 : 0);
#pragma unroll
        for (int nj = 0; nj < 4; ++nj) {
          int gcol = cbase + nj * 16 + lm;
          float v = fmaxf(acc[mi][nj][r] + bias[gcol], 0.f);
          ((float*)Cv)[orow * 2048 + colofs + gcol] = v;
        }
      }
  } else if constexpr (MODE == 1) {
#pragma unroll
    for (int mi = 0; mi < 4; ++mi)
#pragma unroll
      for (int r = 0; r < 4; ++r) {
        float s = 0.f;
#pragma unroll
        for (int nj = 0; nj < 4; ++nj) {
          int gcol = cbase + nj * 16 + lm;
          float v = fmaxf(acc[mi][nj][r] + bias[gcol], 0.f);
          s = fmaf(v, x1[gcol], s);
        }
#pragma unroll
        for (int off = 1; off < 16; off <<= 1) s += __shfl_xor(s, off);
        if (lm == 0) red2[wr * 64 + mi * 16 + kg * 4 + r][wc] = s;
      }
    __syncthreads();
    if (tid < BM) {
      int gm = m0 + tid;
      if (gm < M) part[(size_t)gm * 8 + bx] = red2[tid][0] + red2[tid][1];
    }
  }
}

// C[i] = maybe_relu(sum_z P[z*MN+i] + bias[i%N])
__global__ __launch_bounds__(256) void ksum_k(const float* __restrict__ P,
    const float* __restrict__ bias, int do_relu, float* __restrict__ C,
    int MN, int N, int S)
{
  int i = blockIdx.x * 256 + threadIdx.x;
  if (i < MN) {
    float s = 0.f;
    for (int z = 0; z < S; ++z) s += P[(size_t)z * MN + i];
    if (bias) s += bias[i % N];
    C[i] = do_relu ? fmaxf(s, 0.f) : s;
  }
}

// tw[h,j] = sum_n soft[h,n] * relu(uO[n,j] * V[(h*384+n),j])   (V bf16)
__global__ __launch_bounds__(256) void tw_k(const unsigned short* __restrict__ V,
    const float* __restrict__ uO, const float* __restrict__ soft, float* __restrict__ tw)
{
  int h = blockIdx.x;
  int j = blockIdx.y * 256 + threadIdx.x;
  const float* srow = soft + h * NNN;
  float s = 0.f;
  for (int n = 0; n < NNN; ++n) {
    float v = bf2f(V[((size_t)h * NNN + n) * NEC + j]);
    float t = fmaxf(uO[(size_t)n * NEC + j] * v, 0.f);
    s = fmaf(srow[n], t, s);
  }
  tw[(size_t)h * NEC + j] = s;
}

// two[n,j] = sum_h softT[n,h] * relu(uS[h,j] * V[(h*384+n),j])   (V bf16)
__global__ __launch_bounds__(256) void two_k(const unsigned short* __restrict__ V,
    const float* __restrict__ uS, const float* __restrict__ softT, float* __restrict__ two)
{
  int n = blockIdx.x;
  int j = blockIdx.y * 256 + threadIdx.x;
  const float* srow = softT + n * NHH;
  float s = 0.f;
#pragma unroll 8
  for (int h = 0; h < NHH; ++h) {
    float v = bf2f(V[((size_t)h * NNN + n) * NEC + j]);
    float t = fmaxf(uS[(size_t)h * NEC + j] * v, 0.f);
    s = fmaf(srow[h], t, s);
  }
  two[(size_t)n * NEC + j] = s;
}

__global__ void adjfin_k(const float* __restrict__ part, const float* __restrict__ badj,
                         float* __restrict__ adj)
{
  int p = blockIdx.x * blockDim.x + threadIdx.x;
  if (p < NP) {
    float s = badj[0];
#pragma unroll
    for (int c = 0; c < 8; ++c) s += part[(size_t)p * 8 + c];
    adj[p] = s;
  }
}

__global__ __launch_bounds__(64) void softmax_row_k(const float* __restrict__ adj,
                                                    float* __restrict__ soft)
{
  __shared__ float buf[NNN];
  int h = blockIdx.x, t = threadIdx.x;
  float mx = -1e30f;
  for (int n = t; n < NNN; n += 64) { float v = adj[h * NNN + n]; buf[n] = v; mx = fmaxf(mx, v); }
#pragma unroll
  for (int off = 32; off >= 1; off >>= 1) mx = fmaxf(mx, __shfl_xor(mx, off));
  float s = 0.f;
  for (int n = t; n < NNN; n += 64) { float e = expf(buf[n] - mx); buf[n] = e; s += e; }
#pragma unroll
  for (int off = 32; off >= 1; off >>= 1) s += __shfl_xor(s, off);
  float inv = 1.f / s;
  for (int n = t; n < NNN; n += 64) soft[h * NNN + n] = buf[n] * inv;
}

__global__ __launch_bounds__(64) void softmaxT_k(const float* __restrict__ adj,
                                                 float* __restrict__ softT)
{
  int n = blockIdx.x, t = threadIdx.x;
  float v = (t < NHH) ? adj[t * NNN + n] : -1e30f;
  float mx = v;
#pragma unroll
  for (int off = 32; off >= 1; off >>= 1) mx = fmaxf(mx, __shfl_xor(mx, off));
  float e = (t < NHH) ? expf(v - mx) : 0.f;
  float s = e;
#pragma unroll
  for (int off = 32; off >= 1; off >>= 1) s += __shfl_xor(s, off);
  if (t < NHH) softT[n * NHH + t] = e / s;
}

__global__ __launch_bounds__(256) void ln_k(const float* __restrict__ x, const float* __restrict__ m,
    const float* __restrict__ g, const float* __restrict__ b, float* __restrict__ out)
{
  int r = blockIdx.x, t = threadIdx.x;
  __shared__ float rs[4], rs2[4];
  const float* xr = x + (size_t)r * NEC;
  const float* mr = m + (size_t)r * NEC;
  float s = 0.f, s2 = 0.f;
  for (int j = t; j < NEC; j += 256) { float v = xr[j] + mr[j]; s += v; s2 = fmaf(v, v, s2); }
#pragma unroll
  for (int off = 32; off >= 1; off >>= 1) { s += __shfl_xor(s, off); s2 += __shfl_xor(s2, off); }
  if ((t & 63) == 0) { rs[t >> 6] = s; rs2[t >> 6] = s2; }
  __syncthreads();
  s = rs[0] + rs[1] + rs[2] + rs[3];
  s2 = rs2[0] + rs2[1] + rs2[2] + rs2[3];
  float mean = s * (1.f / NEC);
  float var = s2 * (1.f / NEC) - mean * mean;
  float rstd = rsqrtf(var + 1e-5f);
  float* o = out + (size_t)r * NEC;
  for (int j = t; j < NEC; j += 256) {
    float v = xr[j] + mr[j];
    o[j] = (v - mean) * rstd * g[j] + b[j];
  }
}

__global__ __launch_bounds__(64) void gfeat_k(const float* __restrict__ feat3,
                                              float* __restrict__ gfeat)
{
  int ch = blockIdx.x, t = threadIdx.x;
  float s = 0.f;
  for (int i = t; i < 625; i += 64) s += feat3[ch * 625 + i];
#pragma unroll
  for (int off = 32; off >= 1; off >>= 1) s += __shfl_xor(s, off);
  if (t == 0) gfeat[ch] = s * (1.f / 625.f);
}

__global__ __launch_bounds__(256) void b3sum_k(const float* __restrict__ b3,
                                               float* __restrict__ out)
{
  int r = blockIdx.x * 256 + threadIdx.x;
  if (r < NEC) {
    float s = 0.f;
#pragma unroll
    for (int c = 0; c < 16; ++c) s += b3[c * NEC + r];
    out[r] = s;
  }
}

extern "C" void kernel_launch(void* const* d_in, const int* in_sizes, int n_in,
                              void* d_out, int out_size, void* d_ws, size_t ws_size,
                              hipStream_t stream)
{
  const float* box   = (const float*)d_in[0];
  const float* feat3 = (const float*)d_in[1];
  const float* sp36  = (const float*)d_in[2];
  const float* Wbh1  = (const float*)d_in[3];
  const float* bbh1  = (const float*)d_in[4];
  const float* Wbh2  = (const float*)d_in[5];
  const float* bbh2  = (const float*)d_in[6];
  const float* Wsp1  = (const float*)d_in[7];
  const float* bsp1  = (const float*)d_in[8];
  const float* Wsp2  = (const float*)d_in[9];
  const float* bsp2  = (const float*)d_in[10];
  const float* Wsp3  = (const float*)d_in[11];
  const float* bsp3  = (const float*)d_in[12];
  const float* Wadj  = (const float*)d_in[13];
  const float* badj  = (const float*)d_in[14];
  const float* A1W = (const float*)d_in[15]; const float* A1b = (const float*)d_in[16];
  const float* A2W = (const float*)d_in[17]; const float* A2b = (const float*)d_in[18];
  const float* A3W = (const float*)d_in[19]; const float* A3b = (const float*)d_in[20];
  const float* O1W = (const float*)d_in[21]; const float* O1b = (const float*)d_in[22];
  const float* O2W = (const float*)d_in[23]; const float* O2b = (const float*)d_in[24];
  const float* O3W = (const float*)d_in[25]; const float* O3b = (const float*)d_in[26];
  const float* S1W = (const float*)d_in[27]; const float* S1b = (const float*)d_in[28];
  const float* S2W = (const float*)d_in[29]; const float* S2b = (const float*)d_in[30];
  const float* S3W = (const float*)d_in[31]; const float* S3b = (const float*)d_in[32];
  const float* G1W = (const float*)d_in[33]; const float* G1b = (const float*)d_in[34];
  const float* G2W = (const float*)d_in[35]; const float* G2b = (const float*)d_in[36];
  const float* G3W = (const float*)d_in[37]; const float* G3b = (const float*)d_in[38];
  const float* gln_h = (const float*)d_in[39]; const float* bln_h = (const float*)d_in[40];
  const float* gln_o = (const float*)d_in[41]; const float* bln_o = (const float*)d_in[42];
  (void)in_sizes; (void)n_in; (void)out_size; (void)ws_size;

  // ---- workspace carve (~102 MB) ----
  char* base = (char*)d_ws;
  unsigned short* Vb  = (unsigned short*)base;                  // NP*NEC bf16 (37.7 MB)
  float* partial      = (float*)base;                           // alias: split-K partials (<=12.6 MB)
  unsigned short* s1  = Vb;                                     // alias: sp MLP stage 1 (NP*128)
  unsigned short* s2  = Vb + (size_t)NP * 128;                  // alias: sp MLP stage 2 (NP*256)
  unsigned short* SPb = (unsigned short*)(base + (size_t)NP * NEC * 2);  // NP*NEC bf16
  float* f = (float*)(base + (size_t)NP * NEC * 4);
  size_t off = 0;
  auto alloc = [&](size_t n) { float* p = f + off; off += n; return p; };
  float* node1 = alloc(384 * NEC);
  float* node  = alloc(384 * NEC);
  float* hnode1= alloc(48 * NEC);
  float* node2 = alloc(384 * NEC);
  float* uhA   = alloc(48 * NEC);
  float* unA   = alloc(384 * NEC);
  float* uO    = alloc(384 * NEC);
  float* uS    = alloc(48 * NEC);
  float* uh2   = alloc(48 * NEC);
  float* un2   = alloc(384 * NEC);
  float* uG    = alloc(NEC);
  float* gfeat = alloc(256);
  float* b3A = alloc(NEC); float* b3O = alloc(NEC); float* b3S = alloc(NEC); float* b3G = alloc(NEC);
  float* part  = alloc((size_t)NP * 8);
  float* adj   = alloc(NP);
  float* soft  = alloc(NP);
  float* softT = alloc(NP);
  float* twb   = alloc(48 * NEC);
  float* twob  = alloc(384 * NEC);
  float* m_h   = alloc(48 * NEC);
  float* m_o   = alloc(384 * NEC);
  // bf16 [N][K] transposed weights (persist whole call)
  unsigned short* wb = (unsigned short*)(f + off);
  size_t wo = 0;
  auto walloc = [&](size_t n) { unsigned short* p = wb + wo; wo += n; return p; };
  unsigned short* A2Wb  = walloc((size_t)NEC * NEC);
  unsigned short* O2Wb  = walloc((size_t)NEC * NEC);
  unsigned short* S2Wb  = walloc((size_t)NEC * NEC);
  unsigned short* G2Wb  = walloc((size_t)NEC * NEC);
  unsigned short* A3Wb  = walloc((size_t)NEC * NEC);
  unsigned short* G3Wb  = walloc((size_t)NEC * NEC);
  unsigned short* Wsp3b = walloc((size_t)NEC * 256);
  unsigned short* Wsp2b = walloc((size_t)256 * 128);

  // split-K f32 GEMM: MODE5 slices + ksum reduce (partial aliases Vb; only
  // legal when V is dead -- all call sites verified sequential-safe)
  auto gS = [&](const float* A, const float* B, long long lb, float* C,
                int M, int N, int K, const float* bias, int relu, int S) {
    int Ks = ((K + S * BK - 1) / (S * BK)) * BK;
    dim3 grid(N / BN, (M + BM - 1) / BM, S);
    hipLaunchKernelGGL((gemm_mfma<5, 0, 0, 0>), grid, dim3(256), 0, stream,
                       A, B, lb, nullptr, M, N, K, Ks, nullptr, 0,
                       nullptr, nullptr, partial, 0, 0);
    int MN = M * N;
    hipLaunchKernelGGL(ksum_k, dim3((MN + 255) / 256), dim3(256), 0, stream,
                       partial, bias, relu, C, MN, N, S);
  };
  auto convw = [&](const float* W, unsigned short* Wb2, int K, int N, int blocked) {
    dim3 g(K / 64, N / 64);
    hipLaunchKernelGGL(convw_k, g, dim3(256), 0, stream, W, Wb2, K, N, blocked);
  };

  // ---- weight pre-conversion (one-time, ~25 MB traffic) ----
  convw(A2W, A2Wb, NEC, NEC, 1);
  convw(O2W, O2Wb, NEC, NEC, 1);
  convw(S2W, S2Wb, NEC, NEC, 1);
  convw(G2W, G2Wb, NEC, NEC, 1);
  convw(A3W, A3Wb, NEC, NEC, 0);
  convw(G3W, G3Wb, NEC, NEC, 0);
  convw(Wsp3, Wsp3b, 256, NEC, 0);
  convw(Wsp2, Wsp2b, 128, 256, 0);

  gfeat_k<<<256, 64, 0, stream>>>(feat3, gfeat);
  b3sum_k<<<4, 256, 0, stream>>>(A3b, b3A);
  b3sum_k<<<4, 256, 0, stream>>>(O3b, b3O);
  b3sum_k<<<4, 256, 0, stream>>>(S3b, b3S);
  b3sum_k<<<4, 256, 0, stream>>>(G3b, b3G);

  // node MLP (split-K; partial aliases Vb, dead here)
  gS(box,   Wbh1, 0, node1, 384, NEC, 12544, bbh1, 1, 8);
  gS(node1, Wbh2, 0, node,  384, NEC, NEC,   bbh2, 1, 8);

  // spatial MLP -> SPb (bf16), staging s1/s2 alias Vb
  {
    dim3 g1(1, NP / BM); dim3 g2(2, NP / BM); dim3 g3(8, NP / BM);
    hipLaunchKernelGGL((gemm_mfma<0, 0, 0, 1>), g1, dim3(256), 0, stream,
                       sp36, Wsp1, 0LL, s1, NP, 128, 36, 36, bsp1, 1, nullptr, nullptr, nullptr, 0, 0);
    hipLaunchKernelGGL((gemm_mfma<0, 1, 1, 1>), g2, dim3(256), 0, stream,
                       s1, Wsp2b, 0LL, s2, NP, 256, 128, 128, bsp2, 1, nullptr, nullptr, nullptr, 0, 0);
    hipLaunchKernelGGL((gemm_mfma<0, 1, 1, 1>), g3, dim3(256), 0, stream,
                       s2, Wsp3b, 0LL, SPb, NP, NEC, 256, 256, bsp3, 1, nullptr, nullptr, nullptr, 0, 1);
  }

  dim3 gBig(8, NP / BM);

  // ---- adjacency head ----
  gS(node, A1W,             2048LL * 64, uhA, 48,  NEC, NEC, A1b,    0, 8);
  gS(node, A1W + 1024 * 64, 2048LL * 64, unA, 384, NEC, NEC, nullptr, 0, 8);
  hipLaunchKernelGGL((gemm_mfma<4, 1, 1, 1>), gBig, dim3(256), 0, stream,   // V = relu((uh+un)*(SP@A2W+b2))
                     SPb, A2Wb, 0LL, Vb, NP, NEC, NEC, NEC, A2b, 0, uhA, unA, nullptr, 0, 1);
  hipLaunchKernelGGL((gemm_mfma<1, 1, 1, 0>), gBig, dim3(256), 0, stream,   // adj partials
                     Vb, A3Wb, 0LL, nullptr, NP, NEC, NEC, NEC, b3A, 1, Wadj, nullptr, part, 0, 1);
  adjfin_k<<<(NP + 255) / 256, 256, 0, stream>>>(part, badj, adj);
  softmax_row_k<<<NHH, 64, 0, stream>>>(adj, soft);
  softmaxT_k<<<NNN, 64, 0, stream>>>(adj, softT);

  // ---- m_h (O head) ----
  gS(node, O1W, 1024LL * 64, uO, 384, NEC, NEC, O1b, 0, 8);
  hipLaunchKernelGGL((gemm_mfma<0, 1, 1, 1>), gBig, dim3(256), 0, stream,   // vO
                     SPb, O2Wb, 0LL, Vb, NP, NEC, NEC, NEC, O2b, 0, nullptr, nullptr, nullptr, 0, 1);
  tw_k<<<dim3(NHH, 4), 256, 0, stream>>>(Vb, uO, soft, twb);
  gS(twb, O3W, 0, m_h, 48, NEC, NEC, b3O, 1, 8);
  ln_k<<<NHH, 256, 0, stream>>>(node, m_h, gln_h, bln_h, hnode1);

  // ---- m_o (S head) ----
  gS(hnode1, S1W, 1024LL * 64, uS, 48, NEC, NEC, S1b, 0, 8);
  hipLaunchKernelGGL((gemm_mfma<0, 1, 1, 1>), gBig, dim3(256), 0, stream,   // vS
                     SPb, S2Wb, 0LL, Vb, NP, NEC, NEC, NEC, S2b, 0, nullptr, nullptr, nullptr, 0, 1);
  two_k<<<dim3(NNN, 4), 256, 0, stream>>>(Vb, uS, softT, twob);
  gS(twob, S3W, 0, m_o, 384, NEC, NEC, b3S, 1, 8);
  ln_k<<<NNN, 256, 0, stream>>>(node, m_o, gln_o, bln_o, node2);

  // ---- f_pair ----
  gS(hnode1, A1W,             2048LL * 64, uh2, 48,  NEC, NEC, A1b,    0, 8);
  gS(node2,  A1W + 1024 * 64, 2048LL * 64, un2, 384, NEC, NEC, nullptr, 0, 8);
  hipLaunchKernelGGL((gemm_mfma<4, 1, 1, 1>), gBig, dim3(256), 0, stream,
                     SPb, A2Wb, 0LL, Vb, NP, NEC, NEC, NEC, A2b, 0, uh2, un2, nullptr, 0, 1);
  hipLaunchKernelGGL((gemm_mfma<2, 1, 1, 0>), gBig, dim3(256), 0, stream,
                     Vb, A3Wb, 0LL, (float*)d_out, NP, NEC, NEC, NEC, b3A, 1, nullptr, nullptr, nullptr, 0, 1);

  // ---- f_glob ----
  {
    dim3 g1(8, 1);
    hipLaunchKernelGGL((gemm_mfma<0, 0, 0, 0>), g1, dim3(256), 0, stream,
                       gfeat, G1W, 256LL * 64, uG, 1, NEC, 256, 256, G1b, 0, nullptr, nullptr, nullptr, 0, 0);
  }
  hipLaunchKernelGGL((gemm_mfma<3, 1, 1, 1>), gBig, dim3(256), 0, stream,   // V = relu(ug*(SP@G2W+b2))
                     SPb, G2Wb, 0LL, Vb, NP, NEC, NEC, NEC, G2b, 0, uG, nullptr, nullptr, 0, 1);
  hipLaunchKernelGGL((gemm_mfma<2, 1, 1, 0>), gBig, dim3(256), 0, stream,
                     Vb, G3Wb, 0LL, (float*)d_out, NP, NEC, NEC, NEC, b3G, 1, nullptr, nullptr, nullptr, 1024, 1);
}

// Round 7
// 974.412 us; speedup vs baseline: 13.0577x; 1.2625x over previous
//
#include <hip/hip_runtime.h>
#include <math.h>

#define NHH 48
#define NNN 384
#define NP  18432   // NHH*NNN
#define NEC 1024

#define BM 128
#define BN 128
#define BK 32
#define KPAD 40     // padded bf16 elems per LDS row

typedef __attribute__((ext_vector_type(8))) short short8v;   // 8 bf16 (4 VGPR)
typedef __attribute__((ext_vector_type(4))) float f32x4;     // MFMA acc

__device__ __forceinline__ unsigned short f2bf(float x) {
  unsigned int u = __float_as_uint(x);
  u += 0x7fffu + ((u >> 16) & 1u);   // RNE
  return (unsigned short)(u >> 16);
}
__device__ __forceinline__ float bf2f(unsigned short b) {
  return __uint_as_float(((unsigned)b) << 16);
}

// ---------------------------------------------------------------------------
// Weight pre-convert: f32 -> bf16, output transposed to [N][K].
// ---------------------------------------------------------------------------
__global__ __launch_bounds__(256) void convw_k(const float* __restrict__ in,
    unsigned short* __restrict__ out, int K, int N, int blocked)
{
  __shared__ float t[64][65];
  int kb = blockIdx.x * 64, nb = blockIdx.y * 64;
  const float* src; size_t stride;
  if (blocked) { src = in + (size_t)(nb >> 6) * K * 64; stride = 64; }
  else         { src = in + nb; stride = N; }
  for (int i = threadIdx.x; i < 64 * 64; i += 256) {
    int k = i >> 6, d = i & 63;
    t[d][k] = src[(size_t)(kb + k) * stride + d];
  }
  __syncthreads();
  for (int i = threadIdx.x; i < 64 * 64; i += 256) {
    int d = i >> 6, k = i & 63;
    out[(size_t)(nb + d) * K + kb + k] = f2bf(t[d][k]);
  }
}

// ---------------------------------------------------------------------------
// Unified bf16-MFMA GEMM with register-prefetch K-loop (T14-lite).
// A: f32 (converted at staging) or bf16 (ABF16). B: BBF16=1 pre-transposed
// bf16 [N][K]; else f32 (ldbBlock==0 row-major [K,N], else col-block-64).
// swz=1: 2D XCD remap, grid must be (8,144).
// swz=2: 3D split-K XCD remap; requires (gridDim.y*gridDim.z)%8==0; the 8
//        x-blocks sharing an A-panel land on one XCD, z-major tile order.
// MODE 0: C = maybe_relu(acc + bias)
// MODE 1: part[grow*8+bx] = sum_j relu(acc+bias)*x1[j]
// MODE 2: d_out[orow*2048 + colofs + j] = relu(acc+bias), skip diag pairs
// MODE 3: C = relu(x1[j] * (acc+bias))
// MODE 4: C = relu((x1[row/384]+x2[row%384])[j] * (acc+bias))
// MODE 5: part[(z*M+row)*N+j] = acc      (split-K slice)
// ---------------------------------------------------------------------------
template<int MODE, int ABF16, int BBF16, int CBF16>
__global__ __launch_bounds__(256) void gemm_mfma(
    const void* __restrict__ Av, const void* __restrict__ Bv, long long ldbBlock,
    void* __restrict__ Cv, int M, int N, int K, int Ks,
    const float* __restrict__ bias, int do_relu,
    const float* __restrict__ x1, const float* __restrict__ x2,
    float* __restrict__ part, int colofs, int swz)
{
  __shared__ unsigned short As[BM * KPAD];
  __shared__ unsigned short Bs[BN * KPAD];
  __shared__ float red2[BM][2];

  const float* Af = (const float*)Av;
  const unsigned short* Ab = (const unsigned short*)Av;
  const float* Bf = (const float*)Bv;
  const unsigned short* Bb = (const unsigned short*)Bv;

  const int tid  = threadIdx.x;
  const int lane = tid & 63;
  const int wave = tid >> 6;
  const int wr = wave >> 1, wc = wave & 1;
  const int lm = lane & 15;
  const int kg = lane >> 4;

  int bx = blockIdx.x, by = blockIdx.y, bz = blockIdx.z;
  if (swz == 1) {               // grid (8,144)
    int L = by * 8 + bx;
    int r = L & 7, q = L >> 3;
    bx = q / 18;
    by = r + 8 * (q - bx * 18);
  } else if (swz == 2) {        // grid (8, gy, gz), gy*gz % 8 == 0
    int gy = gridDim.y;
    int ntile = gy * gridDim.z;
    int L = (bz * gy + by) * 8 + bx;
    int r = L & 7, q = L >> 3;
    int tpx = ntile >> 3;
    int tile = r * tpx + (q >> 3);
    bx = q & 7;
    bz = tile / gy;
    by = tile - bz * gy;
  }
  const int m0 = by * BM, n0 = bx * BN;
  const int kbeg = bz * Ks;
  const int kend = min(K, kbeg + Ks);

  f32x4 acc[4][4];
#pragma unroll
  for (int i = 0; i < 4; ++i)
#pragma unroll
    for (int j = 0; j < 4; ++j)
      acc[i][j] = (f32x4){0.f, 0.f, 0.f, 0.f};

  // f32-B staging precompute
  const int bn = tid & 127;
  const int kb = (tid >> 7) * 16;
  const float* bsrc = nullptr; long long bstride = 0;
  if constexpr (!BBF16) {
    int gcol = n0 + bn;
    if (ldbBlock) { bsrc = Bf + (long long)(gcol >> 6) * ldbBlock + (gcol & 63); bstride = 64; }
    else          { bsrc = Bf + gcol; bstride = N; }
  }

  // ---- prefetch registers ----
  uint4 pa0 = {0,0,0,0}, pa1 = {0,0,0,0};          // ABF16 A payload
  uint2 qa0 = {0,0}, qa1 = {0,0}, qa2 = {0,0}, qa3 = {0,0};  // f32-A payload
  uint4 pb0 = {0,0,0,0}, pb1 = {0,0,0,0};          // B payload

  auto fetchA = [&](int k0) {
    if constexpr (ABF16) {
      int m = tid >> 1, kh = (tid & 1) * 16;
      int gm = m0 + m;
      pa0 = (uint4){0,0,0,0}; pa1 = (uint4){0,0,0,0};
      if (gm < M) {
        const uint4* s = (const uint4*)(Ab + (size_t)gm * K + k0 + kh);
        pa0 = s[0]; pa1 = s[1];
      }
    } else {
#define LOADA_F32(J, DST) { \
      int m = (tid >> 3) + J * 32; int k = (tid & 7) * 4; \
      int gm = m0 + m, gk = k0 + k; \
      float x0=0.f, x1v=0.f, x2v=0.f, x3=0.f; \
      if (gm < M) { const float* src = Af + (long long)gm * K + gk; \
        if (gk + 3 < K) { float4 v = *(const float4*)src; x0=v.x; x1v=v.y; x2v=v.z; x3=v.w; } \
        else { if (gk < K) x0 = src[0]; if (gk+1 < K) x1v = src[1]; \
               if (gk+2 < K) x2v = src[2]; if (gk+3 < K) x3 = src[3]; } } \
      DST.x = (unsigned)f2bf(x0)  | ((unsigned)f2bf(x1v) << 16); \
      DST.y = (unsigned)f2bf(x2v) | ((unsigned)f2bf(x3)  << 16); }
      LOADA_F32(0, qa0) LOADA_F32(1, qa1) LOADA_F32(2, qa2) LOADA_F32(3, qa3)
#undef LOADA_F32
    }
  };
  auto fetchB = [&](int k0) {
    if constexpr (BBF16) {
      int nrow = tid >> 1, kh = (tid & 1) * 16;
      const uint4* s = (const uint4*)(Bb + (size_t)(n0 + nrow) * K + k0 + kh);
      pb0 = s[0]; pb1 = s[1];
    } else {
#define PACKB(I, DST) { int g0 = k0 + kb + 2*I, g1 = g0 + 1; \
      float a = (g0 < K) ? bsrc[(long long)g0 * bstride] : 0.f; \
      float c = (g1 < K) ? bsrc[(long long)g1 * bstride] : 0.f; \
      DST = (unsigned)f2bf(a) | ((unsigned)f2bf(c) << 16); }
      PACKB(0, pb0.x) PACKB(1, pb0.y) PACKB(2, pb0.z) PACKB(3, pb0.w)
      PACKB(4, pb1.x) PACKB(5, pb1.y) PACKB(6, pb1.z) PACKB(7, pb1.w)
#undef PACKB
    }
  };
  auto stage = [&]() {
    if constexpr (ABF16) {
      int m = tid >> 1, kh = (tid & 1) * 16;
      *(uint4*)&As[m * KPAD + kh]     = pa0;
      *(uint4*)&As[m * KPAD + kh + 8] = pa1;
    } else {
      int m = tid >> 3, k = (tid & 7) * 4;
      *(uint2*)&As[(m      ) * KPAD + k] = qa0;
      *(uint2*)&As[(m +  32) * KPAD + k] = qa1;
      *(uint2*)&As[(m +  64) * KPAD + k] = qa2;
      *(uint2*)&As[(m +  96) * KPAD + k] = qa3;
    }
    if constexpr (BBF16) {
      int nrow = tid >> 1, kh = (tid & 1) * 16;
      *(uint4*)&Bs[nrow * KPAD + kh]     = pb0;
      *(uint4*)&Bs[nrow * KPAD + kh + 8] = pb1;
    } else {
      *(uint4*)&Bs[bn * KPAD + kb]     = pb0;
      *(uint4*)&Bs[bn * KPAD + kb + 8] = pb1;
    }
  };

  fetchA(kbeg); fetchB(kbeg);
  for (int k0 = kbeg; k0 < kend; k0 += BK) {
    stage();
    int kn = k0 + BK;
    if (kn < kend) { fetchA(kn); fetchB(kn); }   // issue next tile early
    __syncthreads();
    {
      const int lk = kg * 8;
      short8v af[4], bfr[4];
#pragma unroll
      for (int mi = 0; mi < 4; ++mi)
        af[mi] = *(const short8v*)&As[(wr * 64 + mi * 16 + lm) * KPAD + lk];
#pragma unroll
      for (int nj = 0; nj < 4; ++nj)
        bfr[nj] = *(const short8v*)&Bs[(wc * 64 + nj * 16 + lm) * KPAD + lk];
#pragma unroll
      for (int mi = 0; mi < 4; ++mi)
#pragma unroll
        for (int nj = 0; nj < 4; ++nj)
          acc[mi][nj] = __builtin_amdgcn_mfma_f32_16x16x32_bf16(af[mi], bfr[nj], acc[mi][nj], 0, 0, 0);
    }
    __syncthreads();
  }

  const int rbase = m0 + wr * 64;
  const int cbase = n0 + wc * 64;

  if constexpr (MODE == 0 || MODE == 3 || MODE == 4) {
#pragma unroll
    for (int mi = 0; mi < 4; ++mi)
#pragma unroll
      for (int r = 0; r < 4; ++r) {
        int grow = rbase + mi * 16 + kg * 4 + r;
        if (grow >= M) continue;
        int h = 0, n = 0;
        if constexpr (MODE == 4) { h = grow / NNN; n = grow - h * NNN; }
#pragma unroll
        for (int nj = 0; nj < 4; ++nj) {
          int gcol = cbase + nj * 16 + lm;
          float t = acc[mi][nj][r] + (bias ? bias[gcol] : 0.f);
          float v;
          if constexpr (MODE == 3)      v = fmaxf(x1[gcol] * t, 0.f);
          else if constexpr (MODE == 4) v = fmaxf((x1[(size_t)h * NEC + gcol] + x2[(size_t)n * NEC + gcol]) * t, 0.f);
          else                          v = do_relu ? fmaxf(t, 0.f) : t;
          size_t idx = (size_t)grow * N + gcol;
          if constexpr (CBF16) ((unsigned short*)Cv)[idx] = f2bf(v);
          else                 ((float*)Cv)[idx] = v;
        }
      }
  } else if constexpr (MODE == 5) {
    size_t zofs = (size_t)bz * M;
#pragma unroll
    for (int mi = 0; mi < 4; ++mi)
#pragma unroll
      for (int r = 0; r < 4; ++r) {
        int grow = rbase + mi * 16 + kg * 4 + r;
        if (grow >= M) continue;
#pragma unroll
        for (int nj = 0; nj < 4; ++nj) {
          int gcol = cbase + nj * 16 + lm;
          part[(zofs + grow) * N + gcol] = acc[mi][nj][r];
        }
      }
  } else if constexpr (MODE == 2) {
#pragma unroll
    for (int mi = 0; mi < 4; ++mi)
#pragma unroll
      for (int r = 0; r < 4; ++r) {
        int grow = rbase + mi * 16 + kg * 4 + r;
        if (grow >= M) continue;
        int h = grow / NNN, n = grow - h * NNN;
        if (n == h) continue;
        long long orow = grow - h - (n > h ? 1 : 0);
#pragma unroll
        for (int nj = 0; nj < 4; ++nj) {
          int gcol = cbase + nj * 16 + lm;
          float v = fmaxf(acc[mi][nj][r] + bias[gcol], 0.f);
          ((float*)Cv)[orow * 2048 + colofs + gcol] = v;
        }
      }
  } else if constexpr (MODE == 1) {
#pragma unroll
    for (int mi = 0; mi < 4; ++mi)
#pragma unroll
      for (int r = 0; r < 4; ++r) {
        float s = 0.f;
#pragma unroll
        for (int nj = 0; nj < 4; ++nj) {
          int gcol = cbase + nj * 16 + lm;
          float v = fmaxf(acc[mi][nj][r] + bias[gcol], 0.f);
          s = fmaf(v, x1[gcol], s);
        }
#pragma unroll
        for (int off = 1; off < 16; off <<= 1) s += __shfl_xor(s, off);
        if (lm == 0) red2[wr * 64 + mi * 16 + kg * 4 + r][wc] = s;
      }
    __syncthreads();
    if (tid < BM) {
      int gm = m0 + tid;
      if (gm < M) part[(size_t)gm * 8 + bx] = red2[tid][0] + red2[tid][1];
    }
  }
}

// C[i] = maybe_relu(sum_z P[z*MN+i] + bias[i%N])
__global__ __launch_bounds__(256) void ksum_k(const float* __restrict__ P,
    const float* __restrict__ bias, int do_relu, float* __restrict__ C,
    int MN, int N, int S)
{
  int i = blockIdx.x * 256 + threadIdx.x;
  if (i < MN) {
    float s = 0.f;
    for (int z = 0; z < S; ++z) s += P[(size_t)z * MN + i];
    if (bias) s += bias[i % N];
    C[i] = do_relu ? fmaxf(s, 0.f) : s;
  }
}

// tw[h,j] = sum_n soft[h,n] * relu(uO[n,j] * V[(h*384+n),j])   (V bf16)
__global__ __launch_bounds__(256) void tw_k(const unsigned short* __restrict__ V,
    const float* __restrict__ uO, const float* __restrict__ soft, float* __restrict__ tw)
{
  int h = blockIdx.x;
  int j = blockIdx.y * 256 + threadIdx.x;
  const float* srow = soft + h * NNN;
  float s = 0.f;
  for (int n = 0; n < NNN; ++n) {
    float v = bf2f(V[((size_t)h * NNN + n) * NEC + j]);
    float t = fmaxf(uO[(size_t)n * NEC + j] * v, 0.f);
    s = fmaf(srow[n], t, s);
  }
  tw[(size_t)h * NEC + j] = s;
}

// two[n,j] = sum_h softT[n,h] * relu(uS[h,j] * V[(h*384+n),j])   (V bf16)
__global__ __launch_bounds__(256) void two_k(const unsigned short* __restrict__ V,
    const float* __restrict__ uS, const float* __restrict__ softT, float* __restrict__ two)
{
  int n = blockIdx.x;
  int j = blockIdx.y * 256 + threadIdx.x;
  const float* srow = softT + n * NHH;
  float s = 0.f;
#pragma unroll 8
  for (int h = 0; h < NHH; ++h) {
    float v = bf2f(V[((size_t)h * NNN + n) * NEC + j]);
    float t = fmaxf(uS[(size_t)h * NEC + j] * v, 0.f);
    s = fmaf(srow[h], t, s);
  }
  two[(size_t)n * NEC + j] = s;
}

__global__ void adjfin_k(const float* __restrict__ part, const float* __restrict__ badj,
                         float* __restrict__ adj)
{
  int p = blockIdx.x * blockDim.x + threadIdx.x;
  if (p < NP) {
    float s = badj[0];
#pragma unroll
    for (int c = 0; c < 8; ++c) s += part[(size_t)p * 8 + c];
    adj[p] = s;
  }
}

__global__ __launch_bounds__(64) void softmax_row_k(const float* __restrict__ adj,
                                                    float* __restrict__ soft)
{
  __shared__ float buf[NNN];
  int h = blockIdx.x, t = threadIdx.x;
  float mx = -1e30f;
  for (int n = t; n < NNN; n += 64) { float v = adj[h * NNN + n]; buf[n] = v; mx = fmaxf(mx, v); }
#pragma unroll
  for (int off = 32; off >= 1; off >>= 1) mx = fmaxf(mx, __shfl_xor(mx, off));
  float s = 0.f;
  for (int n = t; n < NNN; n += 64) { float e = expf(buf[n] - mx); buf[n] = e; s += e; }
#pragma unroll
  for (int off = 32; off >= 1; off >>= 1) s += __shfl_xor(s, off);
  float inv = 1.f / s;
  for (int n = t; n < NNN; n += 64) soft[h * NNN + n] = buf[n] * inv;
}

__global__ __launch_bounds__(64) void softmaxT_k(const float* __restrict__ adj,
                                                 float* __restrict__ softT)
{
  int n = blockIdx.x, t = threadIdx.x;
  float v = (t < NHH) ? adj[t * NNN + n] : -1e30f;
  float mx = v;
#pragma unroll
  for (int off = 32; off >= 1; off >>= 1) mx = fmaxf(mx, __shfl_xor(mx, off));
  float e = (t < NHH) ? expf(v - mx) : 0.f;
  float s = e;
#pragma unroll
  for (int off = 32; off >= 1; off >>= 1) s += __shfl_xor(s, off);
  if (t < NHH) softT[n * NHH + t] = e / s;
}

__global__ __launch_bounds__(256) void ln_k(const float* __restrict__ x, const float* __restrict__ m,
    const float* __restrict__ g, const float* __restrict__ b, float* __restrict__ out)
{
  int r = blockIdx.x, t = threadIdx.x;
  __shared__ float rs[4], rs2[4];
  const float* xr = x + (size_t)r * NEC;
  const float* mr = m + (size_t)r * NEC;
  float s = 0.f, s2 = 0.f;
  for (int j = t; j < NEC; j += 256) { float v = xr[j] + mr[j]; s += v; s2 = fmaf(v, v, s2); }
#pragma unroll
  for (int off = 32; off >= 1; off >>= 1) { s += __shfl_xor(s, off); s2 += __shfl_xor(s2, off); }
  if ((t & 63) == 0) { rs[t >> 6] = s; rs2[t >> 6] = s2; }
  __syncthreads();
  s = rs[0] + rs[1] + rs[2] + rs[3];
  s2 = rs2[0] + rs2[1] + rs2[2] + rs2[3];
  float mean = s * (1.f / NEC);
  float var = s2 * (1.f / NEC) - mean * mean;
  float rstd = rsqrtf(var + 1e-5f);
  float* o = out + (size_t)r * NEC;
  for (int j = t; j < NEC; j += 256) {
    float v = xr[j] + mr[j];
    o[j] = (v - mean) * rstd * g[j] + b[j];
  }
}

__global__ __launch_bounds__(64) void gfeat_k(const float* __restrict__ feat3,
                                              float* __restrict__ gfeat)
{
  int ch = blockIdx.x, t = threadIdx.x;
  float s = 0.f;
  for (int i = t; i < 625; i += 64) s += feat3[ch * 625 + i];
#pragma unroll
  for (int off = 32; off >= 1; off >>= 1) s += __shfl_xor(s, off);
  if (t == 0) gfeat[ch] = s * (1.f / 625.f);
}

__global__ __launch_bounds__(256) void b3sum_k(const float* __restrict__ b3,
                                               float* __restrict__ out)
{
  int r = blockIdx.x * 256 + threadIdx.x;
  if (r < NEC) {
    float s = 0.f;
#pragma unroll
    for (int c = 0; c < 16; ++c) s += b3[c * NEC + r];
    out[r] = s;
  }
}

extern "C" void kernel_launch(void* const* d_in, const int* in_sizes, int n_in,
                              void* d_out, int out_size, void* d_ws, size_t ws_size,
                              hipStream_t stream)
{
  const float* box   = (const float*)d_in[0];
  const float* feat3 = (const float*)d_in[1];
  const float* sp36  = (const float*)d_in[2];
  const float* Wbh1  = (const float*)d_in[3];
  const float* bbh1  = (const float*)d_in[4];
  const float* Wbh2  = (const float*)d_in[5];
  const float* bbh2  = (const float*)d_in[6];
  const float* Wsp1  = (const float*)d_in[7];
  const float* bsp1  = (const float*)d_in[8];
  const float* Wsp2  = (const float*)d_in[9];
  const float* bsp2  = (const float*)d_in[10];
  const float* Wsp3  = (const float*)d_in[11];
  const float* bsp3  = (const float*)d_in[12];
  const float* Wadj  = (const float*)d_in[13];
  const float* badj  = (const float*)d_in[14];
  const float* A1W = (const float*)d_in[15]; const float* A1b = (const float*)d_in[16];
  const float* A2W = (const float*)d_in[17]; const float* A2b = (const float*)d_in[18];
  const float* A3W = (const float*)d_in[19]; const float* A3b = (const float*)d_in[20];
  const float* O1W = (const float*)d_in[21]; const float* O1b = (const float*)d_in[22];
  const float* O2W = (const float*)d_in[23]; const float* O2b = (const float*)d_in[24];
  const float* O3W = (const float*)d_in[25]; const float* O3b = (const float*)d_in[26];
  const float* S1W = (const float*)d_in[27]; const float* S1b = (const float*)d_in[28];
  const float* S2W = (const float*)d_in[29]; const float* S2b = (const float*)d_in[30];
  const float* S3W = (const float*)d_in[31]; const float* S3b = (const float*)d_in[32];
  const float* G1W = (const float*)d_in[33]; const float* G1b = (const float*)d_in[34];
  const float* G2W = (const float*)d_in[35]; const float* G2b = (const float*)d_in[36];
  const float* G3W = (const float*)d_in[37]; const float* G3b = (const float*)d_in[38];
  const float* gln_h = (const float*)d_in[39]; const float* bln_h = (const float*)d_in[40];
  const float* gln_o = (const float*)d_in[41]; const float* bln_o = (const float*)d_in[42];
  (void)in_sizes; (void)n_in; (void)out_size; (void)ws_size;

  // ---- workspace carve ----
  char* base = (char*)d_ws;
  unsigned short* Vb  = (unsigned short*)base;                  // NP*NEC bf16
  float* partial      = (float*)base;                           // split-K partials (box: 50.3 MB, spills into dead SPb)
  unsigned short* s1  = Vb;                                     // sp MLP stage 1
  unsigned short* s2  = Vb + (size_t)NP * 128;                  // sp MLP stage 2
  unsigned short* SPb = (unsigned short*)(base + (size_t)NP * NEC * 2);
  float* f = (float*)(base + (size_t)NP * NEC * 4);
  size_t off = 0;
  auto alloc = [&](size_t n) { float* p = f + off; off += n; return p; };
  float* node1 = alloc(384 * NEC);
  float* node  = alloc(384 * NEC);
  float* hnode1= alloc(48 * NEC);
  float* node2 = alloc(384 * NEC);
  float* uhA   = alloc(48 * NEC);
  float* unA   = alloc(384 * NEC);
  float* uO    = alloc(384 * NEC);
  float* uS    = alloc(48 * NEC);
  float* uh2   = alloc(48 * NEC);
  float* un2   = alloc(384 * NEC);
  float* uG    = alloc(NEC);
  float* gfeat = alloc(256);
  float* b3A = alloc(NEC); float* b3O = alloc(NEC); float* b3S = alloc(NEC); float* b3G = alloc(NEC);
  float* part  = alloc((size_t)NP * 8);
  float* adj   = alloc(NP);
  float* soft  = alloc(NP);
  float* softT = alloc(NP);
  float* twb   = alloc(48 * NEC);
  float* twob  = alloc(384 * NEC);
  float* m_h   = alloc(48 * NEC);
  float* m_o   = alloc(384 * NEC);
  // bf16 [N][K] transposed weights (persist whole call)
  unsigned short* wb = (unsigned short*)(f + off);
  size_t wo = 0;
  auto walloc = [&](size_t n) { unsigned short* p = wb + wo; wo += n; return p; };
  unsigned short* A2Wb  = walloc((size_t)NEC * NEC);
  unsigned short* O2Wb  = walloc((size_t)NEC * NEC);
  unsigned short* S2Wb  = walloc((size_t)NEC * NEC);
  unsigned short* G2Wb  = walloc((size_t)NEC * NEC);
  unsigned short* A3Wb  = walloc((size_t)NEC * NEC);
  unsigned short* G3Wb  = walloc((size_t)NEC * NEC);
  unsigned short* Wsp3b = walloc((size_t)NEC * 256);
  unsigned short* Wsp2b = walloc((size_t)256 * 128);

  // split-K f32 GEMM: MODE5 slices (XCD-swizzled) + ksum reduce.
  // partial aliases Vb(+SPb for box) -- all call sites verified dead there.
  auto gS = [&](const float* A, const float* B, long long lb, float* C,
                int M, int N, int K, const float* bias, int relu, int S) {
    int Ks = ((K + S * BK - 1) / (S * BK)) * BK;
    dim3 grid(N / BN, (M + BM - 1) / BM, S);
    hipLaunchKernelGGL((gemm_mfma<5, 0, 0, 0>), grid, dim3(256), 0, stream,
                       A, B, lb, nullptr, M, N, K, Ks, nullptr, 0,
                       nullptr, nullptr, partial, 0, 2);
    int MN = M * N;
    hipLaunchKernelGGL(ksum_k, dim3((MN + 255) / 256), dim3(256), 0, stream,
                       partial, bias, relu, C, MN, N, S);
  };
  auto convw = [&](const float* W, unsigned short* Wb2, int K, int N, int blocked) {
    dim3 g(K / 64, N / 64);
    hipLaunchKernelGGL(convw_k, g, dim3(256), 0, stream, W, Wb2, K, N, blocked);
  };

  // ---- weight pre-conversion (one-time) ----
  convw(A2W, A2Wb, NEC, NEC, 1);
  convw(O2W, O2Wb, NEC, NEC, 1);
  convw(S2W, S2Wb, NEC, NEC, 1);
  convw(G2W, G2Wb, NEC, NEC, 1);
  convw(A3W, A3Wb, NEC, NEC, 0);
  convw(G3W, G3Wb, NEC, NEC, 0);
  convw(Wsp3, Wsp3b, 256, NEC, 0);
  convw(Wsp2, Wsp2b, 128, 256, 0);

  gfeat_k<<<256, 64, 0, stream>>>(feat3, gfeat);
  b3sum_k<<<4, 256, 0, stream>>>(A3b, b3A);
  b3sum_k<<<4, 256, 0, stream>>>(O3b, b3O);
  b3sum_k<<<4, 256, 0, stream>>>(S3b, b3S);
  b3sum_k<<<4, 256, 0, stream>>>(G3b, b3G);

  // node MLP (deep split-K; box partial spills into dead SPb region)
  gS(box,   Wbh1, 0, node1, 384, NEC, 12544, bbh1, 1, 32);
  gS(node1, Wbh2, 0, node,  384, NEC, NEC,   bbh2, 1, 16);

  // spatial MLP -> SPb (bf16), staging s1/s2 alias Vb
  {
    dim3 g1(1, NP / BM); dim3 g2(2, NP / BM); dim3 g3(8, NP / BM);
    hipLaunchKernelGGL((gemm_mfma<0, 0, 0, 1>), g1, dim3(256), 0, stream,
                       sp36, Wsp1, 0LL, s1, NP, 128, 36, 36, bsp1, 1, nullptr, nullptr, nullptr, 0, 0);
    hipLaunchKernelGGL((gemm_mfma<0, 1, 1, 1>), g2, dim3(256), 0, stream,
                       s1, Wsp2b, 0LL, s2, NP, 256, 128, 128, bsp2, 1, nullptr, nullptr, nullptr, 0, 0);
    hipLaunchKernelGGL((gemm_mfma<0, 1, 1, 1>), g3, dim3(256), 0, stream,
                       s2, Wsp3b, 0LL, SPb, NP, NEC, 256, 256, bsp3, 1, nullptr, nullptr, nullptr, 0, 1);
  }

  dim3 gBig(8, NP / BM);

  // ---- adjacency head ----
  gS(node, A1W,             2048LL * 64, uhA, 48,  NEC, NEC, A1b,    0, 16);
  gS(node, A1W + 1024 * 64, 2048LL * 64, unA, 384, NEC, NEC, nullptr, 0, 16);
  hipLaunchKernelGGL((gemm_mfma<4, 1, 1, 1>), gBig, dim3(256), 0, stream,   // V = relu((uh+un)*(SP@A2W+b2))
                     SPb, A2Wb, 0LL, Vb, NP, NEC, NEC, NEC, A2b, 0, uhA, unA, nullptr, 0, 1);
  hipLaunchKernelGGL((gemm_mfma<1, 1, 1, 0>), gBig, dim3(256), 0, stream,   // adj partials
                     Vb, A3Wb, 0LL, nullptr, NP, NEC, NEC, NEC, b3A, 1, Wadj, nullptr, part, 0, 1);
  adjfin_k<<<(NP + 255) / 256, 256, 0, stream>>>(part, badj, adj);
  softmax_row_k<<<NHH, 64, 0, stream>>>(adj, soft);
  softmaxT_k<<<NNN, 64, 0, stream>>>(adj, softT);

  // ---- m_h (O head) ----
  gS(node, O1W, 1024LL * 64, uO, 384, NEC, NEC, O1b, 0, 16);
  hipLaunchKernelGGL((gemm_mfma<0, 1, 1, 1>), gBig, dim3(256), 0, stream,   // vO
                     SPb, O2Wb, 0LL, Vb, NP, NEC, NEC, NEC, O2b, 0, nullptr, nullptr, nullptr, 0, 1);
  tw_k<<<dim3(NHH, 4), 256, 0, stream>>>(Vb, uO, soft, twb);
  gS(twb, O3W, 0, m_h, 48, NEC, NEC, b3O, 1, 16);
  ln_k<<<NHH, 256, 0, stream>>>(node, m_h, gln_h, bln_h, hnode1);

  // ---- m_o (S head) ----
  gS(hnode1, S1W, 1024LL * 64, uS, 48, NEC, NEC, S1b, 0, 16);
  hipLaunchKernelGGL((gemm_mfma<0, 1, 1, 1>), gBig, dim3(256), 0, stream,   // vS
                     SPb, S2Wb, 0LL, Vb, NP, NEC, NEC, NEC, S2b, 0, nullptr, nullptr, nullptr, 0, 1);
  two_k<<<dim3(NNN, 4), 256, 0, stream>>>(Vb, uS, softT, twob);
  gS(twob, S3W, 0, m_o, 384, NEC, NEC, b3S, 1, 16);
  ln_k<<<NNN, 256, 0, stream>>>(node, m_o, gln_o, bln_o, node2);

  // ---- f_pair ----
  gS(hnode1, A1W,             2048LL * 64, uh2, 48,  NEC, NEC, A1b,    0, 16);
  gS(node2,  A1W + 1024 * 64, 2048LL * 64, un2, 384, NEC, NEC, nullptr, 0, 16);
  hipLaunchKernelGGL((gemm_mfma<4, 1, 1, 1>), gBig, dim3(256), 0, stream,
                     SPb, A2Wb, 0LL, Vb, NP, NEC, NEC, NEC, A2b, 0, uh2, un2, nullptr, 0, 1);
  hipLaunchKernelGGL((gemm_mfma<2, 1, 1, 0>), gBig, dim3(256), 0, stream,
                     Vb, A3Wb, 0LL, (float*)d_out, NP, NEC, NEC, NEC, b3A, 1, nullptr, nullptr, nullptr, 0, 1);

  // ---- f_glob ----
  {
    dim3 g1(8, 1);
    hipLaunchKernelGGL((gemm_mfma<0, 0, 0, 0>), g1, dim3(256), 0, stream,
                       gfeat, G1W, 256LL * 64, uG, 1, NEC, 256, 256, G1b, 0, nullptr, nullptr, nullptr, 0, 0);
  }
  hipLaunchKernelGGL((gemm_mfma<3, 1, 1, 1>), gBig, dim3(256), 0, stream,   // V = relu(ug*(SP@G2W+b2))
                     SPb, G2Wb, 0LL, Vb, NP, NEC, NEC, NEC, G2b, 0, uG, nullptr, nullptr, 0, 1);
  hipLaunchKernelGGL((gemm_mfma<2, 1, 1, 0>), gBig, dim3(256), 0, stream,
                     Vb, G3Wb, 0LL, (float*)d_out, NP, NEC, NEC, NEC, b3G, 1, nullptr, nullptr, nullptr, 1024, 1);
}

// Round 8
// 916.580 us; speedup vs baseline: 13.8816x; 1.0631x over previous
//
#include <hip/hip_runtime.h>
#include <math.h>

#define NHH 48
#define NNN 384
#define NP  18432   // NHH*NNN
#define NEC 1024

#define BM 128
#define BN 128
#define BK 32
#define KPAD 40     // padded bf16 elems per LDS row (80B rows: uniform bank spread)

typedef __attribute__((ext_vector_type(8))) short short8v;   // 8 bf16 (4 VGPR)
typedef __attribute__((ext_vector_type(4))) float f32x4;     // MFMA acc

__device__ __forceinline__ unsigned short f2bf(float x) {
  unsigned int u = __float_as_uint(x);
  u += 0x7fffu + ((u >> 16) & 1u);   // RNE
  return (unsigned short)(u >> 16);
}
__device__ __forceinline__ float bf2f(unsigned short b) {
  return __uint_as_float(((unsigned)b) << 16);
}

// ---------------------------------------------------------------------------
// Weight pre-convert: f32 -> bf16, output transposed to [N][K].
// ---------------------------------------------------------------------------
__global__ __launch_bounds__(256) void convw_k(const float* __restrict__ in,
    unsigned short* __restrict__ out, int K, int N, int blocked)
{
  __shared__ float t[64][65];
  int kb = blockIdx.x * 64, nb = blockIdx.y * 64;
  const float* src; size_t stride;
  if (blocked) { src = in + (size_t)(nb >> 6) * K * 64; stride = 64; }
  else         { src = in + nb; stride = N; }
  for (int i = threadIdx.x; i < 64 * 64; i += 256) {
    int k = i >> 6, d = i & 63;
    t[d][k] = src[(size_t)(kb + k) * stride + d];
  }
  __syncthreads();
  for (int i = threadIdx.x; i < 64 * 64; i += 256) {
    int d = i >> 6, k = i & 63;
    out[(size_t)(nb + d) * K + kb + k] = f2bf(t[d][k]);
  }
}

// ---------------------------------------------------------------------------
// gemm_big: 512-thread, 8-wave (2x4), bf16 A [M][K] / bf16 B [N][K] GEMM.
// Per wave 64x32 output (acc 4x2), 2-deep register prefetch, 128x128 tile.
// Requires: M,N multiples of 128; K multiple of 64.
// swz=1: XCD remap, grid must be (8,144).
// MODE 0: C = maybe_relu(acc + bias)
// MODE 1: part[grow*8+bx] = sum_j relu(acc+bias)*x1[j]
// MODE 2: d_out[orow*2048 + colofs + j] = relu(acc+bias), skip diag pairs
// MODE 3: C = relu(x1[j] * (acc+bias))
// MODE 4: C = relu((x1[row/384]+x2[row%384])[j] * (acc+bias))
// ---------------------------------------------------------------------------
template<int MODE, int CBF16>
__global__ __launch_bounds__(512, 4) void gemm_big(
    const unsigned short* __restrict__ A, const unsigned short* __restrict__ B,
    void* __restrict__ Cv, int M, int N, int K,
    const float* __restrict__ bias, int do_relu,
    const float* __restrict__ x1, const float* __restrict__ x2,
    float* __restrict__ part, int colofs, int swz)
{
  __shared__ unsigned short As[BM * KPAD];
  __shared__ unsigned short Bs[BN * KPAD];
  __shared__ float red4[BM][4];

  const int tid  = threadIdx.x;
  const int lane = tid & 63;
  const int wave = tid >> 6;        // 0..7
  const int wr = wave >> 2;         // 0..1  (row half)
  const int wc = wave & 3;          // 0..3  (col quarter)
  const int lm = lane & 15;
  const int kg = lane >> 4;

  int bx = blockIdx.x, by = blockIdx.y;
  if (swz) {                        // grid (8,144)
    int L = by * 8 + bx;
    int r = L & 7, q = L >> 3;
    bx = q / 18;
    by = r + 8 * (q - bx * 18);
  }
  const int m0 = by * BM, n0 = bx * BN;

  f32x4 acc[4][2];
#pragma unroll
  for (int i = 0; i < 4; ++i)
#pragma unroll
    for (int j = 0; j < 2; ++j)
      acc[i][j] = (f32x4){0.f, 0.f, 0.f, 0.f};

  const int sr = tid >> 2;          // 0..127 staging row
  const int sc = (tid & 3) * 8;     // staging col (elems): 0,8,16,24
  const unsigned short* aptr = A + (size_t)(m0 + sr) * K + sc;
  const unsigned short* bptr = B + (size_t)(n0 + sr) * K + sc;
  const int ldsOff = sr * KPAD + sc;

  uint4 a0, b0, a1, b1;
  a0 = *(const uint4*)(aptr);
  b0 = *(const uint4*)(bptr);
  if (BK < K) { a1 = *(const uint4*)(aptr + BK); b1 = *(const uint4*)(bptr + BK); }

  auto compute = [&]() {
    const int lk = kg * 8;
    short8v af[4], bfr[2];
#pragma unroll
    for (int mi = 0; mi < 4; ++mi)
      af[mi] = *(const short8v*)&As[(wr * 64 + mi * 16 + lm) * KPAD + lk];
#pragma unroll
    for (int nj = 0; nj < 2; ++nj)
      bfr[nj] = *(const short8v*)&Bs[(wc * 32 + nj * 16 + lm) * KPAD + lk];
#pragma unroll
    for (int mi = 0; mi < 4; ++mi)
#pragma unroll
      for (int nj = 0; nj < 2; ++nj)
        acc[mi][nj] = __builtin_amdgcn_mfma_f32_16x16x32_bf16(af[mi], bfr[nj], acc[mi][nj], 0, 0, 0);
  };

  for (int k0 = 0; k0 < K; k0 += 2 * BK) {
    // step A (tile k0) from regs a0/b0
    *(uint4*)&As[ldsOff] = a0;
    *(uint4*)&Bs[ldsOff] = b0;
    if (k0 + 2 * BK < K) { a0 = *(const uint4*)(aptr + k0 + 2 * BK); b0 = *(const uint4*)(bptr + k0 + 2 * BK); }
    __syncthreads();
    compute();
    __syncthreads();
    // step B (tile k0+BK) from regs a1/b1
    *(uint4*)&As[ldsOff] = a1;
    *(uint4*)&Bs[ldsOff] = b1;
    if (k0 + 3 * BK < K) { a1 = *(const uint4*)(aptr + k0 + 3 * BK); b1 = *(const uint4*)(bptr + k0 + 3 * BK); }
    __syncthreads();
    compute();
    __syncthreads();
  }

  const int rbase = m0 + wr * 64;
  const int cbase = n0 + wc * 32;

  if constexpr (MODE == 0 || MODE == 3 || MODE == 4) {
#pragma unroll
    for (int mi = 0; mi < 4; ++mi)
#pragma unroll
      for (int r = 0; r < 4; ++r) {
        int grow = rbase + mi * 16 + kg * 4 + r;
        int h = 0, n = 0;
        if constexpr (MODE == 4) { h = grow / NNN; n = grow - h * NNN; }
#pragma unroll
        for (int nj = 0; nj < 2; ++nj) {
          int gcol = cbase + nj * 16 + lm;
          float t = acc[mi][nj][r] + (bias ? bias[gcol] : 0.f);
          float v;
          if constexpr (MODE == 3)      v = fmaxf(x1[gcol] * t, 0.f);
          else if constexpr (MODE == 4) v = fmaxf((x1[(size_t)h * NEC + gcol] + x2[(size_t)n * NEC + gcol]) * t, 0.f);
          else                          v = do_relu ? fmaxf(t, 0.f) : t;
          size_t idx = (size_t)grow * N + gcol;
          if constexpr (CBF16) ((unsigned short*)Cv)[idx] = f2bf(v);
          else                 ((float*)Cv)[idx] = v;
        }
      }
  } else if constexpr (MODE == 2) {
#pragma unroll
    for (int mi = 0; mi < 4; ++mi)
#pragma unroll
      for (int r = 0; r < 4; ++r) {
        int grow = rbase + mi * 16 + kg * 4 + r;
        int h = grow / NNN, n = grow - h * NNN;
        if (n == h) continue;
        long long orow = grow - h - (n > h ? 1 : 0);
#pragma unroll
        for (int nj = 0; nj < 2; ++nj) {
          int gcol = cbase + nj * 16 + lm;
          float v = fmaxf(acc[mi][nj][r] + bias[gcol], 0.f);
          ((float*)Cv)[orow * 2048 + colofs + gcol] = v;
        }
      }
  } else if constexpr (MODE == 1) {
#pragma unroll
    for (int mi = 0; mi < 4; ++mi)
#pragma unroll
      for (int r = 0; r < 4; ++r) {
        float s = 0.f;
#pragma unroll
        for (int nj = 0; nj < 2; ++nj) {
          int gcol = cbase + nj * 16 + lm;
          float v = fmaxf(acc[mi][nj][r] + bias[gcol], 0.f);
          s = fmaf(v, x1[gcol], s);
        }
#pragma unroll
        for (int off2 = 1; off2 < 16; off2 <<= 1) s += __shfl_xor(s, off2);
        if (lm == 0) red4[wr * 64 + mi * 16 + kg * 4 + r][wc] = s;
      }
    __syncthreads();
    if (tid < BM) {
      part[(size_t)(m0 + tid) * 8 + bx] = red4[tid][0] + red4[tid][1] + red4[tid][2] + red4[tid][3];
    }
  }
}

// ---------------------------------------------------------------------------
// 256-thread unified GEMM (f32 A paths): split-K MODE5 + MODE0.
// ---------------------------------------------------------------------------
template<int MODE, int ABF16, int BBF16, int CBF16>
__global__ __launch_bounds__(256) void gemm_mfma(
    const void* __restrict__ Av, const void* __restrict__ Bv, long long ldbBlock,
    void* __restrict__ Cv, int M, int N, int K, int Ks,
    const float* __restrict__ bias, int do_relu,
    const float* __restrict__ x1, const float* __restrict__ x2,
    float* __restrict__ part, int colofs, int swz)
{
  __shared__ unsigned short As[BM * KPAD];
  __shared__ unsigned short Bs[BN * KPAD];

  const float* Af = (const float*)Av;
  const unsigned short* Ab = (const unsigned short*)Av;
  const float* Bf = (const float*)Bv;
  const unsigned short* Bb = (const unsigned short*)Bv;

  const int tid  = threadIdx.x;
  const int lane = tid & 63;
  const int wave = tid >> 6;
  const int wr = wave >> 1, wc = wave & 1;
  const int lm = lane & 15;
  const int kg = lane >> 4;

  int bx = blockIdx.x, by = blockIdx.y, bz = blockIdx.z;
  if (swz == 2) {               // grid (8, gy, gz), gy*gz % 8 == 0
    int gy = gridDim.y;
    int ntile = gy * gridDim.z;
    int L = (bz * gy + by) * 8 + bx;
    int r = L & 7, q = L >> 3;
    int tpx = ntile >> 3;
    int tile = r * tpx + (q >> 3);
    bx = q & 7;
    bz = tile / gy;
    by = tile - bz * gy;
  }
  const int m0 = by * BM, n0 = bx * BN;
  const int kbeg = bz * Ks;
  const int kend = min(K, kbeg + Ks);

  f32x4 acc[4][4];
#pragma unroll
  for (int i = 0; i < 4; ++i)
#pragma unroll
    for (int j = 0; j < 4; ++j)
      acc[i][j] = (f32x4){0.f, 0.f, 0.f, 0.f};

  const int bn = tid & 127;
  const int kb = (tid >> 7) * 16;
  const float* bsrc = nullptr; long long bstride = 0;
  if constexpr (!BBF16) {
    int gcol = n0 + bn;
    if (ldbBlock) { bsrc = Bf + (long long)(gcol >> 6) * ldbBlock + (gcol & 63); bstride = 64; }
    else          { bsrc = Bf + gcol; bstride = N; }
  }

  uint4 pa0 = {0,0,0,0}, pa1 = {0,0,0,0};
  uint2 qa0 = {0,0}, qa1 = {0,0}, qa2 = {0,0}, qa3 = {0,0};
  uint4 pb0 = {0,0,0,0}, pb1 = {0,0,0,0};

  auto fetchA = [&](int k0) {
    if constexpr (ABF16) {
      int m = tid >> 1, kh = (tid & 1) * 16;
      int gm = m0 + m;
      pa0 = (uint4){0,0,0,0}; pa1 = (uint4){0,0,0,0};
      if (gm < M) {
        const uint4* s = (const uint4*)(Ab + (size_t)gm * K + k0 + kh);
        pa0 = s[0]; pa1 = s[1];
      }
    } else {
#define LOADA_F32(J, DST) { \
      int m = (tid >> 3) + J * 32; int k = (tid & 7) * 4; \
      int gm = m0 + m, gk = k0 + k; \
      float x0=0.f, x1v=0.f, x2v=0.f, x3=0.f; \
      if (gm < M) { const float* src = Af + (long long)gm * K + gk; \
        if (gk + 3 < K) { float4 v = *(const float4*)src; x0=v.x; x1v=v.y; x2v=v.z; x3=v.w; } \
        else { if (gk < K) x0 = src[0]; if (gk+1 < K) x1v = src[1]; \
               if (gk+2 < K) x2v = src[2]; if (gk+3 < K) x3 = src[3]; } } \
      DST.x = (unsigned)f2bf(x0)  | ((unsigned)f2bf(x1v) << 16); \
      DST.y = (unsigned)f2bf(x2v) | ((unsigned)f2bf(x3)  << 16); }
      LOADA_F32(0, qa0) LOADA_F32(1, qa1) LOADA_F32(2, qa2) LOADA_F32(3, qa3)
#undef LOADA_F32
    }
  };
  auto fetchB = [&](int k0) {
    if constexpr (BBF16) {
      int nrow = tid >> 1, kh = (tid & 1) * 16;
      const uint4* s = (const uint4*)(Bb + (size_t)(n0 + nrow) * K + k0 + kh);
      pb0 = s[0]; pb1 = s[1];
    } else {
#define PACKB(I, DST) { int g0 = k0 + kb + 2*I, g1 = g0 + 1; \
      float a = (g0 < K) ? bsrc[(long long)g0 * bstride] : 0.f; \
      float c = (g1 < K) ? bsrc[(long long)g1 * bstride] : 0.f; \
      DST = (unsigned)f2bf(a) | ((unsigned)f2bf(c) << 16); }
      PACKB(0, pb0.x) PACKB(1, pb0.y) PACKB(2, pb0.z) PACKB(3, pb0.w)
      PACKB(4, pb1.x) PACKB(5, pb1.y) PACKB(6, pb1.z) PACKB(7, pb1.w)
#undef PACKB
    }
  };
  auto stage = [&]() {
    if constexpr (ABF16) {
      int m = tid >> 1, kh = (tid & 1) * 16;
      *(uint4*)&As[m * KPAD + kh]     = pa0;
      *(uint4*)&As[m * KPAD + kh + 8] = pa1;
    } else {
      int m = tid >> 3, k = (tid & 7) * 4;
      *(uint2*)&As[(m      ) * KPAD + k] = qa0;
      *(uint2*)&As[(m +  32) * KPAD + k] = qa1;
      *(uint2*)&As[(m +  64) * KPAD + k] = qa2;
      *(uint2*)&As[(m +  96) * KPAD + k] = qa3;
    }
    if constexpr (BBF16) {
      int nrow = tid >> 1, kh = (tid & 1) * 16;
      *(uint4*)&Bs[nrow * KPAD + kh]     = pb0;
      *(uint4*)&Bs[nrow * KPAD + kh + 8] = pb1;
    } else {
      *(uint4*)&Bs[bn * KPAD + kb]     = pb0;
      *(uint4*)&Bs[bn * KPAD + kb + 8] = pb1;
    }
  };

  fetchA(kbeg); fetchB(kbeg);
  for (int k0 = kbeg; k0 < kend; k0 += BK) {
    stage();
    int kn = k0 + BK;
    if (kn < kend) { fetchA(kn); fetchB(kn); }
    __syncthreads();
    {
      const int lk = kg * 8;
      short8v af[4], bfr[4];
#pragma unroll
      for (int mi = 0; mi < 4; ++mi)
        af[mi] = *(const short8v*)&As[(wr * 64 + mi * 16 + lm) * KPAD + lk];
#pragma unroll
      for (int nj = 0; nj < 4; ++nj)
        bfr[nj] = *(const short8v*)&Bs[(wc * 64 + nj * 16 + lm) * KPAD + lk];
#pragma unroll
      for (int mi = 0; mi < 4; ++mi)
#pragma unroll
        for (int nj = 0; nj < 4; ++nj)
          acc[mi][nj] = __builtin_amdgcn_mfma_f32_16x16x32_bf16(af[mi], bfr[nj], acc[mi][nj], 0, 0, 0);
    }
    __syncthreads();
  }

  const int rbase = m0 + wr * 64;
  const int cbase = n0 + wc * 64;

  if constexpr (MODE == 0) {
#pragma unroll
    for (int mi = 0; mi < 4; ++mi)
#pragma unroll
      for (int r = 0; r < 4; ++r) {
        int grow = rbase + mi * 16 + kg * 4 + r;
        if (grow >= M) continue;
#pragma unroll
        for (int nj = 0; nj < 4; ++nj) {
          int gcol = cbase + nj * 16 + lm;
          float t = acc[mi][nj][r] + (bias ? bias[gcol] : 0.f);
          float v = do_relu ? fmaxf(t, 0.f) : t;
          size_t idx = (size_t)grow * N + gcol;
          if constexpr (CBF16) ((unsigned short*)Cv)[idx] = f2bf(v);
          else                 ((float*)Cv)[idx] = v;
        }
      }
  } else if constexpr (MODE == 5) {
    size_t zofs = (size_t)bz * M;
#pragma unroll
    for (int mi = 0; mi < 4; ++mi)
#pragma unroll
      for (int r = 0; r < 4; ++r) {
        int grow = rbase + mi * 16 + kg * 4 + r;
        if (grow >= M) continue;
#pragma unroll
        for (int nj = 0; nj < 4; ++nj) {
          int gcol = cbase + nj * 16 + lm;
          part[(zofs + grow) * N + gcol] = acc[mi][nj][r];
        }
      }
  }
}

// C[i] = maybe_relu(sum_z P[z*MN+i] + bias[i%N])
__global__ __launch_bounds__(256) void ksum_k(const float* __restrict__ P,
    const float* __restrict__ bias, int do_relu, float* __restrict__ C,
    int MN, int N, int S)
{
  int i = blockIdx.x * 256 + threadIdx.x;
  if (i < MN) {
    float s = 0.f;
    for (int z = 0; z < S; ++z) s += P[(size_t)z * MN + i];
    if (bias) s += bias[i % N];
    C[i] = do_relu ? fmaxf(s, 0.f) : s;
  }
}

// tw[h,j] = sum_n soft[h,n] * relu(uO[n,j] * V[(h*384+n),j])   (V bf16)
__global__ __launch_bounds__(256) void tw_k(const unsigned short* __restrict__ V,
    const float* __restrict__ uO, const float* __restrict__ soft, float* __restrict__ tw)
{
  int h = blockIdx.x;
  int j = blockIdx.y * 256 + threadIdx.x;
  const float* srow = soft + h * NNN;
  float s = 0.f;
  for (int n = 0; n < NNN; ++n) {
    float v = bf2f(V[((size_t)h * NNN + n) * NEC + j]);
    float t = fmaxf(uO[(size_t)n * NEC + j] * v, 0.f);
    s = fmaf(srow[n], t, s);
  }
  tw[(size_t)h * NEC + j] = s;
}

// two[n,j] = sum_h softT[n,h] * relu(uS[h,j] * V[(h*384+n),j])   (V bf16)
__global__ __launch_bounds__(256) void two_k(const unsigned short* __restrict__ V,
    const float* __restrict__ uS, const float* __restrict__ softT, float* __restrict__ two)
{
  int n = blockIdx.x;
  int j = blockIdx.y * 256 + threadIdx.x;
  const float* srow = softT + n * NHH;
  float s = 0.f;
#pragma unroll 8
  for (int h = 0; h < NHH; ++h) {
    float v = bf2f(V[((size_t)h * NNN + n) * NEC + j]);
    float t = fmaxf(uS[(size_t)h * NEC + j] * v, 0.f);
    s = fmaf(srow[h], t, s);
  }
  two[(size_t)n * NEC + j] = s;
}

__global__ void adjfin_k(const float* __restrict__ part, const float* __restrict__ badj,
                         float* __restrict__ adj)
{
  int p = blockIdx.x * blockDim.x + threadIdx.x;
  if (p < NP) {
    float s = badj[0];
#pragma unroll
    for (int c = 0; c < 8; ++c) s += part[(size_t)p * 8 + c];
    adj[p] = s;
  }
}

__global__ __launch_bounds__(64) void softmax_row_k(const float* __restrict__ adj,
                                                    float* __restrict__ soft)
{
  __shared__ float buf[NNN];
  int h = blockIdx.x, t = threadIdx.x;
  float mx = -1e30f;
  for (int n = t; n < NNN; n += 64) { float v = adj[h * NNN + n]; buf[n] = v; mx = fmaxf(mx, v); }
#pragma unroll
  for (int off = 32; off >= 1; off >>= 1) mx = fmaxf(mx, __shfl_xor(mx, off));
  float s = 0.f;
  for (int n = t; n < NNN; n += 64) { float e = expf(buf[n] - mx); buf[n] = e; s += e; }
#pragma unroll
  for (int off = 32; off >= 1; off >>= 1) s += __shfl_xor(s, off);
  float inv = 1.f / s;
  for (int n = t; n < NNN; n += 64) soft[h * NNN + n] = buf[n] * inv;
}

__global__ __launch_bounds__(64) void softmaxT_k(const float* __restrict__ adj,
                                                 float* __restrict__ softT)
{
  int n = blockIdx.x, t = threadIdx.x;
  float v = (t < NHH) ? adj[t * NNN + n] : -1e30f;
  float mx = v;
#pragma unroll
  for (int off = 32; off >= 1; off >>= 1) mx = fmaxf(mx, __shfl_xor(mx, off));
  float e = (t < NHH) ? expf(v - mx) : 0.f;
  float s = e;
#pragma unroll
  for (int off = 32; off >= 1; off >>= 1) s += __shfl_xor(s, off);
  if (t < NHH) softT[n * NHH + t] = e / s;
}

__global__ __launch_bounds__(256) void ln_k(const float* __restrict__ x, const float* __restrict__ m,
    const float* __restrict__ g, const float* __restrict__ b, float* __restrict__ out)
{
  int r = blockIdx.x, t = threadIdx.x;
  __shared__ float rs[4], rs2[4];
  const float* xr = x + (size_t)r * NEC;
  const float* mr = m + (size_t)r * NEC;
  float s = 0.f, s2 = 0.f;
  for (int j = t; j < NEC; j += 256) { float v = xr[j] + mr[j]; s += v; s2 = fmaf(v, v, s2); }
#pragma unroll
  for (int off = 32; off >= 1; off >>= 1) { s += __shfl_xor(s, off); s2 += __shfl_xor(s2, off); }
  if ((t & 63) == 0) { rs[t >> 6] = s; rs2[t >> 6] = s2; }
  __syncthreads();
  s = rs[0] + rs[1] + rs[2] + rs[3];
  s2 = rs2[0] + rs2[1] + rs2[2] + rs2[3];
  float mean = s * (1.f / NEC);
  float var = s2 * (1.f / NEC) - mean * mean;
  float rstd = rsqrtf(var + 1e-5f);
  float* o = out + (size_t)r * NEC;
  for (int j = t; j < NEC; j += 256) {
    float v = xr[j] + mr[j];
    o[j] = (v - mean) * rstd * g[j] + b[j];
  }
}

__global__ __launch_bounds__(64) void gfeat_k(const float* __restrict__ feat3,
                                              float* __restrict__ gfeat)
{
  int ch = blockIdx.x, t = threadIdx.x;
  float s = 0.f;
  for (int i = t; i < 625; i += 64) s += feat3[ch * 625 + i];
#pragma unroll
  for (int off = 32; off >= 1; off >>= 1) s += __shfl_xor(s, off);
  if (t == 0) gfeat[ch] = s * (1.f / 625.f);
}

__global__ __launch_bounds__(256) void b3sum_k(const float* __restrict__ b3,
                                               float* __restrict__ out)
{
  int r = blockIdx.x * 256 + threadIdx.x;
  if (r < NEC) {
    float s = 0.f;
#pragma unroll
    for (int c = 0; c < 16; ++c) s += b3[c * NEC + r];
    out[r] = s;
  }
}

extern "C" void kernel_launch(void* const* d_in, const int* in_sizes, int n_in,
                              void* d_out, int out_size, void* d_ws, size_t ws_size,
                              hipStream_t stream)
{
  const float* box   = (const float*)d_in[0];
  const float* feat3 = (const float*)d_in[1];
  const float* sp36  = (const float*)d_in[2];
  const float* Wbh1  = (const float*)d_in[3];
  const float* bbh1  = (const float*)d_in[4];
  const float* Wbh2  = (const float*)d_in[5];
  const float* bbh2  = (const float*)d_in[6];
  const float* Wsp1  = (const float*)d_in[7];
  const float* bsp1  = (const float*)d_in[8];
  const float* Wsp2  = (const float*)d_in[9];
  const float* bsp2  = (const float*)d_in[10];
  const float* Wsp3  = (const float*)d_in[11];
  const float* bsp3  = (const float*)d_in[12];
  const float* Wadj  = (const float*)d_in[13];
  const float* badj  = (const float*)d_in[14];
  const float* A1W = (const float*)d_in[15]; const float* A1b = (const float*)d_in[16];
  const float* A2W = (const float*)d_in[17]; const float* A2b = (const float*)d_in[18];
  const float* A3W = (const float*)d_in[19]; const float* A3b = (const float*)d_in[20];
  const float* O1W = (const float*)d_in[21]; const float* O1b = (const float*)d_in[22];
  const float* O2W = (const float*)d_in[23]; const float* O2b = (const float*)d_in[24];
  const float* O3W = (const float*)d_in[25]; const float* O3b = (const float*)d_in[26];
  const float* S1W = (const float*)d_in[27]; const float* S1b = (const float*)d_in[28];
  const float* S2W = (const float*)d_in[29]; const float* S2b = (const float*)d_in[30];
  const float* S3W = (const float*)d_in[31]; const float* S3b = (const float*)d_in[32];
  const float* G1W = (const float*)d_in[33]; const float* G1b = (const float*)d_in[34];
  const float* G2W = (const float*)d_in[35]; const float* G2b = (const float*)d_in[36];
  const float* G3W = (const float*)d_in[37]; const float* G3b = (const float*)d_in[38];
  const float* gln_h = (const float*)d_in[39]; const float* bln_h = (const float*)d_in[40];
  const float* gln_o = (const float*)d_in[41]; const float* bln_o = (const float*)d_in[42];
  (void)in_sizes; (void)n_in; (void)out_size; (void)ws_size;

  // ---- workspace carve ----
  char* base = (char*)d_ws;
  unsigned short* Vb  = (unsigned short*)base;                  // NP*NEC bf16
  float* partial      = (float*)base;                           // split-K partials (box spills into dead SPb)
  unsigned short* s1  = Vb;                                     // sp MLP stage 1
  unsigned short* s2  = Vb + (size_t)NP * 128;                  // sp MLP stage 2
  unsigned short* SPb = (unsigned short*)(base + (size_t)NP * NEC * 2);
  float* f = (float*)(base + (size_t)NP * NEC * 4);
  size_t off = 0;
  auto alloc = [&](size_t n) { float* p = f + off; off += n; return p; };
  float* node1 = alloc(384 * NEC);
  float* node  = alloc(384 * NEC);
  float* hnode1= alloc(48 * NEC);
  float* node2 = alloc(384 * NEC);
  float* uhA   = alloc(48 * NEC);
  float* unA   = alloc(384 * NEC);
  float* uO    = alloc(384 * NEC);
  float* uS    = alloc(48 * NEC);
  float* uh2   = alloc(48 * NEC);
  float* un2   = alloc(384 * NEC);
  float* uG    = alloc(NEC);
  float* gfeat = alloc(256);
  float* b3A = alloc(NEC); float* b3O = alloc(NEC); float* b3S = alloc(NEC); float* b3G = alloc(NEC);
  float* part  = alloc((size_t)NP * 8);
  float* adj   = alloc(NP);
  float* soft  = alloc(NP);
  float* softT = alloc(NP);
  float* twb   = alloc(48 * NEC);
  float* twob  = alloc(384 * NEC);
  float* m_h   = alloc(48 * NEC);
  float* m_o   = alloc(384 * NEC);
  // bf16 [N][K] transposed weights (persist whole call)
  unsigned short* wb = (unsigned short*)(f + off);
  size_t wo = 0;
  auto walloc = [&](size_t n) { unsigned short* p = wb + wo; wo += n; return p; };
  unsigned short* A2Wb  = walloc((size_t)NEC * NEC);
  unsigned short* O2Wb  = walloc((size_t)NEC * NEC);
  unsigned short* S2Wb  = walloc((size_t)NEC * NEC);
  unsigned short* G2Wb  = walloc((size_t)NEC * NEC);
  unsigned short* A3Wb  = walloc((size_t)NEC * NEC);
  unsigned short* G3Wb  = walloc((size_t)NEC * NEC);
  unsigned short* Wsp3b = walloc((size_t)NEC * 256);
  unsigned short* Wsp2b = walloc((size_t)256 * 128);

  auto gS = [&](const float* A, const float* B, long long lb, float* C,
                int M, int N, int K, const float* bias, int relu, int S) {
    int Ks = ((K + S * BK - 1) / (S * BK)) * BK;
    dim3 grid(N / BN, (M + BM - 1) / BM, S);
    hipLaunchKernelGGL((gemm_mfma<5, 0, 0, 0>), grid, dim3(256), 0, stream,
                       A, B, lb, nullptr, M, N, K, Ks, nullptr, 0,
                       nullptr, nullptr, partial, 0, 2);
    int MN = M * N;
    hipLaunchKernelGGL(ksum_k, dim3((MN + 255) / 256), dim3(256), 0, stream,
                       partial, bias, relu, C, MN, N, S);
  };
  auto convw = [&](const float* W, unsigned short* Wb2, int K, int N, int blocked) {
    dim3 g(K / 64, N / 64);
    hipLaunchKernelGGL(convw_k, g, dim3(256), 0, stream, W, Wb2, K, N, blocked);
  };

  // ---- weight pre-conversion (one-time) ----
  convw(A2W, A2Wb, NEC, NEC, 1);
  convw(O2W, O2Wb, NEC, NEC, 1);
  convw(S2W, S2Wb, NEC, NEC, 1);
  convw(G2W, G2Wb, NEC, NEC, 1);
  convw(A3W, A3Wb, NEC, NEC, 0);
  convw(G3W, G3Wb, NEC, NEC, 0);
  convw(Wsp3, Wsp3b, 256, NEC, 0);
  convw(Wsp2, Wsp2b, 128, 256, 0);

  gfeat_k<<<256, 64, 0, stream>>>(feat3, gfeat);
  b3sum_k<<<4, 256, 0, stream>>>(A3b, b3A);
  b3sum_k<<<4, 256, 0, stream>>>(O3b, b3O);
  b3sum_k<<<4, 256, 0, stream>>>(S3b, b3S);
  b3sum_k<<<4, 256, 0, stream>>>(G3b, b3G);

  // node MLP (deep split-K; box partial spills into dead SPb region)
  gS(box,   Wbh1, 0, node1, 384, NEC, 12544, bbh1, 1, 32);
  gS(node1, Wbh2, 0, node,  384, NEC, NEC,   bbh2, 1, 16);

  dim3 gBig(8, NP / BM);

  // spatial MLP -> SPb (bf16), staging s1/s2 alias Vb
  {
    dim3 g1(1, NP / BM); dim3 g2(2, NP / BM);
    hipLaunchKernelGGL((gemm_mfma<0, 0, 0, 1>), g1, dim3(256), 0, stream,
                       sp36, Wsp1, 0LL, s1, NP, 128, 36, 36, bsp1, 1, nullptr, nullptr, nullptr, 0, 0);
    hipLaunchKernelGGL((gemm_big<0, 1>), g2, dim3(512), 0, stream,
                       s1, Wsp2b, s2, NP, 256, 128, bsp2, 1, nullptr, nullptr, nullptr, 0, 0);
    hipLaunchKernelGGL((gemm_big<0, 1>), gBig, dim3(512), 0, stream,
                       s2, Wsp3b, SPb, NP, NEC, 256, bsp3, 1, nullptr, nullptr, nullptr, 0, 1);
  }

  // ---- adjacency head ----
  gS(node, A1W,             2048LL * 64, uhA, 48,  NEC, NEC, A1b,    0, 16);
  gS(node, A1W + 1024 * 64, 2048LL * 64, unA, 384, NEC, NEC, nullptr, 0, 16);
  hipLaunchKernelGGL((gemm_big<4, 1>), gBig, dim3(512), 0, stream,   // V = relu((uh+un)*(SP@A2W+b2))
                     SPb, A2Wb, Vb, NP, NEC, NEC, A2b, 0, uhA, unA, nullptr, 0, 1);
  hipLaunchKernelGGL((gemm_big<1, 0>), gBig, dim3(512), 0, stream,   // adj partials
                     Vb, A3Wb, nullptr, NP, NEC, NEC, b3A, 1, Wadj, nullptr, part, 0, 1);
  adjfin_k<<<(NP + 255) / 256, 256, 0, stream>>>(part, badj, adj);
  softmax_row_k<<<NHH, 64, 0, stream>>>(adj, soft);
  softmaxT_k<<<NNN, 64, 0, stream>>>(adj, softT);

  // ---- m_h (O head) ----
  gS(node, O1W, 1024LL * 64, uO, 384, NEC, NEC, O1b, 0, 16);
  hipLaunchKernelGGL((gemm_big<0, 1>), gBig, dim3(512), 0, stream,   // vO
                     SPb, O2Wb, Vb, NP, NEC, NEC, O2b, 0, nullptr, nullptr, nullptr, 0, 1);
  tw_k<<<dim3(NHH, 4), 256, 0, stream>>>(Vb, uO, soft, twb);
  gS(twb, O3W, 0, m_h, 48, NEC, NEC, b3O, 1, 16);
  ln_k<<<NHH, 256, 0, stream>>>(node, m_h, gln_h, bln_h, hnode1);

  // ---- m_o (S head) ----
  gS(hnode1, S1W, 1024LL * 64, uS, 48, NEC, NEC, S1b, 0, 16);
  hipLaunchKernelGGL((gemm_big<0, 1>), gBig, dim3(512), 0, stream,   // vS
                     SPb, S2Wb, Vb, NP, NEC, NEC, S2b, 0, nullptr, nullptr, nullptr, 0, 1);
  two_k<<<dim3(NNN, 4), 256, 0, stream>>>(Vb, uS, softT, twob);
  gS(twob, S3W, 0, m_o, 384, NEC, NEC, b3S, 1, 16);
  ln_k<<<NNN, 256, 0, stream>>>(node, m_o, gln_o, bln_o, node2);

  // ---- f_pair ----
  gS(hnode1, A1W,             2048LL * 64, uh2, 48,  NEC, NEC, A1b,    0, 16);
  gS(node2,  A1W + 1024 * 64, 2048LL * 64, un2, 384, NEC, NEC, nullptr, 0, 16);
  hipLaunchKernelGGL((gemm_big<4, 1>), gBig, dim3(512), 0, stream,
                     SPb, A2Wb, Vb, NP, NEC, NEC, A2b, 0, uh2, un2, nullptr, 0, 1);
  hipLaunchKernelGGL((gemm_big<2, 0>), gBig, dim3(512), 0, stream,
                     Vb, A3Wb, (float*)d_out, NP, NEC, NEC, b3A, 1, nullptr, nullptr, nullptr, 0, 1);

  // ---- f_glob ----
  {
    dim3 g1(8, 1);
    hipLaunchKernelGGL((gemm_mfma<0, 0, 0, 0>), g1, dim3(256), 0, stream,
                       gfeat, G1W, 256LL * 64, uG, 1, NEC, 256, 256, G1b, 0, nullptr, nullptr, nullptr, 0, 0);
  }
  hipLaunchKernelGGL((gemm_big<3, 1>), gBig, dim3(512), 0, stream,   // V = relu(ug*(SP@G2W+b2))
                     SPb, G2Wb, Vb, NP, NEC, NEC, G2b, 0, uG, nullptr, nullptr, 0, 1);
  hipLaunchKernelGGL((gemm_big<2, 0>), gBig, dim3(512), 0, stream,
                     Vb, G3Wb, (float*)d_out, NP, NEC, NEC, b3G, 1, nullptr, nullptr, nullptr, 1024, 1);
}